// Round 9
// baseline (235.905 us; speedup 1.0000x reference)
//
#include <hip/hip_runtime.h>

// RPN target generation for MI355X — 2-node pipeline (pairs+combine, finalize).
// Outputs (float32, concat): [0,A) rpn_match; [A,5A) rpn_bbox (A x 4); [5A] num_positives.
//
// Calibrated lessons (R2-R8):
//  * same-address device atomics ~100ns/op -> never O(grid) on one address.
//  * DS queue is in-order -> no per-iter LDS atomics/shuffles in the hot loop;
//    per-lane VGPR bitmask + sparse post-loop drain (R5).
//  * best hot loop = G-split halves + 2 anchors/thread (R7 pairs2: 54.5us, 78% VALU).
//  * single-block streaming of O(MB) ws = 100us latency trap (R8 finalize) ->
//    cross-block gt-reduction via 32-way sharded atomicMax (64 KB total).
//  * ~15us/graph-node -> 2 nodes; no memsets: gkeyS keys biased +0xC0000001 so
//    real keys beat 0xAA poison under atomicMax; combiner election via
//    atomicExch(flag,1) (old==1 means "I'm second") works for any poison != 1.
//
// ws layout: [0,2A*8) akey | [+2A*4) cmaxA (crowd only) | [+G*32*8) gkeyS |
//            [+nch*4) chunkdone | [+nch*4) pcount

#define GMAX 256
#define SHARDS 32
#define KBIAS 0xC0000001u   // top-word bias: real keys in [0xC0000002, 0xFF800001]

// Faithful to the reference, including the intentional size "bug":
// gt_size = y2 + y1 (not y2 - y1); centre = 0.5 * (y1 + y2).
__device__ __forceinline__ float4 compute_deltas(float4 ab, float4 gb,
                                                 const float* __restrict__ sd) {
    float sy_g = gb.z + gb.x;   // box = (y1, x1, y2, x2) in (x,y,z,w)
    float sx_g = gb.w + gb.y;
    float sy_a = ab.z + ab.x;
    float sx_a = ab.w + ab.y;
    float4 d;
    d.x = (0.5f * (sy_g - sy_a) / sy_a) / sd[0];
    d.y = (0.5f * (sx_g - sx_a) / sx_a) / sd[1];
    d.z = logf(sy_g / sy_a) / sd[2];
    d.w = logf(sx_g / sx_a) / sd[3];
    return d;
}

__device__ __forceinline__ float iou_of(float4 ab, float a_area, float4 gb) {
    float y1 = fmaxf(ab.x, gb.x);
    float x1 = fmaxf(ab.y, gb.y);
    float y2 = fminf(ab.z, gb.z);
    float x2 = fminf(ab.w, gb.w);
    float inter = fmaxf(y2 - y1, 0.f) * fmaxf(x2 - x1, 0.f);
    float garea = (gb.z - gb.x) * (gb.w - gb.y);
    float uni = (a_area + garea) - inter;
    return inter * __builtin_amdgcn_rcpf(uni);   // exact 0 if inter==0
}

// ---------- kernel 1: pair sweep (half-G, 2 anchors/thread) + chunk combiner ----------
__global__ __launch_bounds__(256) void rpn_pairs3(
    const float4* __restrict__ anchors,       // [A]
    const int* __restrict__ valid,            // [A] jnp bool as int32
    const int* __restrict__ cls,              // [G]
    const float4* __restrict__ gt,            // [G]
    const float* __restrict__ stdev,          // [4]
    float* __restrict__ out,                  // [5A+1]
    unsigned long long* __restrict__ akey,    // [2*A] plain stores
    unsigned* __restrict__ cmaxA,             // [2*A] (crowd only)
    unsigned long long* __restrict__ gkeyS,   // [G*SHARDS] biased keys, poison-ok
    unsigned* __restrict__ chunkdone,         // [nch] election flags, poison-ok
    int* __restrict__ pcount,                 // [nch] plain stores (combiner)
    int A, int G)
{
    __shared__ float4 s_gt[GMAX];             // FULL gt (combiner needs all for deltas)
    __shared__ float s_crowdf[GMAX];
    __shared__ unsigned long long s_key[GMAX / 2];
    __shared__ int s_anycrowd;
    __shared__ int s_cnt;
    __shared__ int s_iscomb;

    const int tid = threadIdx.x;
    const int bi = blockIdx.x;
    const int half = bi & 1;
    const int chunk = bi >> 1;
    const int Gh = (G + 1) >> 1;
    const int g0 = half * Gh;
    const int gn = min(G - g0, Gh);           // 128 for G=256

    if (tid == 0) { s_anycrowd = 0; s_cnt = 0; }
    if (tid < G) {
        s_gt[tid] = gt[tid];
        int c = cls[tid];
        s_crowdf[tid] = (c < 0) ? 1.0f : 0.0f;
        if (c < 0) s_anycrowd = 1;            // benign race, same value
    }
    if (tid < Gh) s_key[tid] = 0ULL;
    __syncthreads();
    const int any_crowd = s_anycrowd;

    const int ai0 = chunk * 512 + tid;
    const int ai1 = ai0 + 256;
    const bool ir0 = (ai0 < A), ir1 = (ai1 < A);
    float4 a0 = ir0 ? anchors[ai0] : make_float4(0.f, 0.f, 1.f, 1.f);
    float4 a1 = ir1 ? anchors[ai1] : make_float4(0.f, 0.f, 1.f, 1.f);
    const bool v0 = ir0 && (valid[ai0] != 0);
    const bool v1 = ir1 && (valid[ai1] != 0);
    const float ar0 = (a0.z - a0.x) * (a0.w - a0.y);
    const float ar1 = (a1.z - a1.x) * (a1.w - a1.y);

    float b0v, b1v;
    int bg0 = g0, bg1 = g0;
    float cm0 = 0.0f, cm1 = 0.0f;
    unsigned long long m00 = 0ULL, m01 = 0ULL, m10 = 0ULL, m11 = 0ULL;

    if (!any_crowd && gn == 128) {
        b0v = -1.0f; b1v = -1.0f;
        #pragma unroll
        for (int w = 0; w < 2; ++w) {
            unsigned long long ma = 0ULL, mb = 0ULL;
            #pragma unroll 4
            for (int j = 0; j < 64; ++j) {
                int gg = (w << 6) + j;
                float4 gb = s_gt[g0 + gg];     // one ds_read_b128 feeds 2 anchors
                float garea = (gb.z - gb.x) * (gb.w - gb.y);
                {
                    float y1 = fmaxf(a0.x, gb.x), x1 = fmaxf(a0.y, gb.y);
                    float y2 = fminf(a0.z, gb.z), x2 = fminf(a0.w, gb.w);
                    float inter = fmaxf(y2 - y1, 0.f) * fmaxf(x2 - x1, 0.f);
                    float iou = inter * __builtin_amdgcn_rcpf((ar0 + garea) - inter);
                    if (iou > b0v) { b0v = iou; bg0 = g0 + gg; }
                    if (iou > 0.0f) ma |= (1ULL << j);
                }
                {
                    float y1 = fmaxf(a1.x, gb.x), x1 = fmaxf(a1.y, gb.y);
                    float y2 = fminf(a1.z, gb.z), x2 = fminf(a1.w, gb.w);
                    float inter = fmaxf(y2 - y1, 0.f) * fmaxf(x2 - x1, 0.f);
                    float iou = inter * __builtin_amdgcn_rcpf((ar1 + garea) - inter);
                    if (iou > b1v) { b1v = iou; bg1 = g0 + gg; }
                    if (iou > 0.0f) mb |= (1ULL << j);
                }
            }
            if (w == 0) { m00 = ma; m10 = mb; } else { m01 = ma; m11 = mb; }
        }
    } else {
        // general path: crowd / odd sizes (correctness-only)
        b0v = -2.0f; b1v = -2.0f;
        for (int gg = 0; gg < gn; ++gg) {
            float4 gb = s_gt[g0 + gg];
            float cf = s_crowdf[g0 + gg];
            float i0 = iou_of(a0, ar0, gb);
            float i1 = iou_of(a1, ar1, gb);
            float e0 = (cf != 0.0f) ? -1.0f : i0;
            float e1 = (cf != 0.0f) ? -1.0f : i1;
            if (e0 > b0v) { b0v = e0; bg0 = g0 + gg; }
            if (e1 > b1v) { b1v = e1; bg1 = g0 + gg; }
            cm0 = fmaxf(cm0, i0 * cf);
            cm1 = fmaxf(cm1, i1 * cf);
            if (cf == 0.0f) {
                if (i0 > 0.0f) { if (gg < 64) m00 |= (1ULL << gg); else m01 |= (1ULL << (gg - 64)); }
                if (i1 > 0.0f) { if (gg < 64) m10 |= (1ULL << gg); else m11 |= (1ULL << (gg - 64)); }
            }
        }
    }

    if (ir0) {
        akey[(size_t)half * A + ai0] =
            (((unsigned long long)__float_as_uint(b0v)) << 32) | (unsigned)bg0;
        if (any_crowd) cmaxA[(size_t)half * A + ai0] = __float_as_uint(cm0);
    }
    if (ir1) {
        akey[(size_t)half * A + ai1] =
            (((unsigned long long)__float_as_uint(b1v)) << 32) | (unsigned)bg1;
        if (any_crowd) cmaxA[(size_t)half * A + ai1] = __float_as_uint(cm1);
    }

    // ---- sparse drain (~2-3 bits/lane/anchor): rare LDS atomicMax ----
    if (v0) {
        const unsigned lokey = ~(unsigned)ai0;
        #pragma unroll
        for (int w = 0; w < 2; ++w) {
            unsigned long long m = (w == 0) ? m00 : m01;
            while (m != 0ULL) {
                int j = __builtin_ctzll(m); m &= (m - 1ULL);
                int gg = (w << 6) + j;
                float iou = iou_of(a0, ar0, s_gt[g0 + gg]);
                atomicMax(&s_key[gg],
                    (((unsigned long long)(__float_as_uint(iou) + KBIAS)) << 32) | lokey);
            }
        }
    }
    if (v1) {
        const unsigned lokey = ~(unsigned)ai1;
        #pragma unroll
        for (int w = 0; w < 2; ++w) {
            unsigned long long m = (w == 0) ? m10 : m11;
            while (m != 0ULL) {
                int j = __builtin_ctzll(m); m &= (m - 1ULL);
                int gg = (w << 6) + j;
                float iou = iou_of(a1, ar1, s_gt[g0 + gg]);
                atomicMax(&s_key[gg],
                    (((unsigned long long)(__float_as_uint(iou) + KBIAS)) << 32) | lokey);
            }
        }
    }
    __syncthreads();

    // sharded global merge: biased keys always beat 0xAA poison under atomicMax
    if (tid < gn && s_key[tid] != 0ULL)
        atomicMax(&gkeyS[(size_t)(g0 + tid) * SHARDS + (chunk & (SHARDS - 1))],
                  s_key[tid]);

    // ---- combiner election: second arrival merges both halves of this chunk ----
    __threadfence();                           // release akey/cmaxA stores
    if (tid == 0) {
        unsigned old = atomicExch(&chunkdone[chunk], 1u);  // poison != 1
        s_iscomb = (old == 1u);
    }
    __syncthreads();
    if (!s_iscomb) return;
    __threadfence();                           // acquire sibling's stores

    #pragma unroll
    for (int t = 0; t < 2; ++t) {
        const int ai = chunk * 512 + t * 256 + tid;
        bool posv = false;
        if (ai < A) {
            unsigned long long k0 = akey[ai];
            unsigned long long k1 = akey[(size_t)A + ai];
            float bb0 = __uint_as_float((unsigned)(k0 >> 32));
            float bb1 = __uint_as_float((unsigned)(k1 >> 32));
            unsigned g_0 = (unsigned)k0, g_1 = (unsigned)k1;
            float best; int bg;
            if (bb1 > bb0 || (bb1 == bb0 && g_1 < g_0)) { best = bb1; bg = (int)g_1; }
            else                                        { best = bb0; bg = (int)g_0; }

            const bool v = (valid[ai] != 0);
            bool no_crowd = true;
            if (any_crowd)
                no_crowd = (fmaxf(__uint_as_float(cmaxA[ai]),
                                  __uint_as_float(cmaxA[(size_t)A + ai])) < 0.001f);
            bool pos = (best >= 0.7f);
            bool neg = (best < 0.3f) && no_crowd && !pos;
            posv = pos && v;

            out[ai] = v ? (pos ? 1.0f : (neg ? -1.0f : 0.0f)) : 0.0f;
            float4 d = make_float4(0.f, 0.f, 0.f, 0.f);
            if (posv) d = compute_deltas(anchors[ai], s_gt[bg], stdev);
            ((float4*)(out + A))[ai] = d;
        }
        unsigned long long pv = __ballot((int)posv);
        if ((tid & 63) == 0) atomicAdd(&s_cnt, (int)__popcll(pv));   // LDS only
    }
    __syncthreads();
    if (tid == 0) pcount[chunk] = s_cnt;       // PLAIN store
}

// ---------- kernel 2: single-block finalize (64 KB reads only) ----------
__global__ __launch_bounds__(256) void rpn_finalize(
    const float4* __restrict__ anchors,
    const int* __restrict__ valid,
    const int* __restrict__ cls,
    const float4* __restrict__ gt,
    const float* __restrict__ stdev,
    float* __restrict__ out,
    const unsigned long long* __restrict__ gkeyS,
    const int* __restrict__ pcount,
    int nch, int A, int G)
{
    __shared__ float4 s_gt[GMAX];
    __shared__ float s_crowdf[GMAX];
    __shared__ int s_tot[256];
    __shared__ int s_cnt;

    const int tid = threadIdx.x;
    if (tid == 0) s_cnt = 0;
    if (tid < G) {
        s_gt[tid] = gt[tid];
        s_crowdf[tid] = (cls[tid] < 0) ? 1.0f : 0.0f;
    }
    int acc = 0;
    for (int i = tid; i < nch; i += 256) acc += pcount[i];
    s_tot[tid] = acc;
    __syncthreads();
    for (int s = 128; s > 0; s >>= 1) {
        if (tid < s) s_tot[tid] += s_tot[tid + s];
        __syncthreads();
    }

    if (tid < G && s_crowdf[tid] == 0.0f) {    // scatter value is False for crowd gts
        unsigned long long key = 0ULL;
        for (int s = 0; s < SHARDS; ++s) {
            unsigned long long k = gkeyS[(size_t)tid * SHARDS + s];
            if (k > key) key = k;
        }
        const bool has = ((unsigned)(key >> 32) >= (KBIAS + 1u));  // poison/0 -> none
        int w;
        if (has) {
            w = (int)(~(unsigned)(key & 0xFFFFFFFFull));
        } else {
            // no valid anchor overlapped this gt: first valid anchor, else 0
            w = 0;
            for (int i = 0; i < A; ++i) { if (valid[i] != 0) { w = i; break; } }
        }
        if (valid[w] != 0) {
            float old = atomicExch(out + w, 1.0f);   // <=256 ops, mostly distinct
            if (old != 1.0f) {
                float4 ab2 = anchors[w];
                float a2 = (ab2.z - ab2.x) * (ab2.w - ab2.y);
                float b2 = -2.0f; int g2 = 0;
                for (int g = 0; g < G; ++g) {
                    float iou = iou_of(ab2, a2, s_gt[g]);
                    float eff = (s_crowdf[g] != 0.0f) ? -1.0f : iou;
                    if (eff > b2) { b2 = eff; g2 = g; }
                }
                ((float4*)(out + A))[w] = compute_deltas(ab2, s_gt[g2], stdev);
                atomicAdd(&s_cnt, 1);
            }
        }
    }
    __syncthreads();
    if (tid == 0) out[(size_t)5 * A] = (float)(s_tot[0] + s_cnt);
}

// ---------------- fallback: monolithic kernel (used only if ws too small) ------
__global__ __launch_bounds__(256) void rpn_fused(
    const float4* __restrict__ anchors, const int* __restrict__ valid,
    const int* __restrict__ cls, const float4* __restrict__ gt,
    const float* __restrict__ stdev, float* __restrict__ out,
    unsigned long long* __restrict__ gkey, unsigned* __restrict__ done,
    int* __restrict__ cnt, int A, int G)
{
    __shared__ float4 s_gt[GMAX];
    __shared__ float s_crowdf[GMAX];
    __shared__ unsigned long long s_key[GMAX];
    __shared__ int s_anycrowd; __shared__ int s_cnt; __shared__ int s_islast;

    const int tid = threadIdx.x;
    if (tid == 0) { s_anycrowd = 0; s_cnt = 0; }
    if (tid < G) {
        s_gt[tid] = gt[tid];
        int c = cls[tid];
        s_crowdf[tid] = (c < 0) ? 1.0f : 0.0f;
        if (c < 0) s_anycrowd = 1;
        s_key[tid] = 0ULL;
    }
    __syncthreads();
    const int any_crowd = s_anycrowd;
    const int ai = blockIdx.x * 256 + tid;
    const bool in_range = (ai < A);
    float4 ab = in_range ? anchors[ai] : make_float4(0.f, 0.f, 1.f, 1.f);
    const bool v = in_range && (valid[ai] != 0);
    const float a_area = (ab.z - ab.x) * (ab.w - ab.y);
    const unsigned lokey = ~(unsigned)ai;

    float best = any_crowd ? -2.0f : -1.0f;
    int bg = 0; float crowd_max = 0.0f;
    unsigned long long ovmask[4];
    #pragma unroll
    for (int w = 0; w < 4; ++w) {
        unsigned long long m = 0ULL;
        #pragma unroll 4
        for (int j = 0; j < 64; ++j) {
            int g = (w << 6) + j;
            if (g >= G) break;
            float iou = iou_of(ab, a_area, s_gt[g]);
            float cf = s_crowdf[g];
            float eff = (any_crowd && cf != 0.0f) ? -1.0f : iou;
            if (eff > best) { best = eff; bg = g; }
            if (any_crowd) crowd_max = fmaxf(crowd_max, iou * cf);
            if (v && (cf == 0.0f) && iou > 0.0f) m |= (1ULL << j);
        }
        ovmask[w] = m;
    }
    #pragma unroll
    for (int w = 0; w < 4; ++w) {
        unsigned long long m = ovmask[w];
        while (m != 0ULL) {
            int j = __builtin_ctzll(m); m &= (m - 1ULL);
            int g = (w << 6) + j;
            float iou = iou_of(ab, a_area, s_gt[g]);
            atomicMax(&s_key[g],
                (((unsigned long long)(__float_as_uint(iou) + 1u)) << 32) | lokey);
        }
    }
    bool no_crowd = any_crowd ? (crowd_max < 0.001f) : true;
    bool pos = (best >= 0.7f);
    bool neg = (best < 0.3f) && no_crowd && !pos;
    unsigned long long pv = __ballot((int)(in_range && pos && v));
    if ((tid & 63) == 0) atomicAdd(&s_cnt, (int)__popcll(pv));
    if (in_range) {
        out[ai] = v ? (pos ? 1.0f : (neg ? -1.0f : 0.0f)) : 0.0f;
        float4 d = make_float4(0.f, 0.f, 0.f, 0.f);
        if (pos && v) d = compute_deltas(ab, s_gt[bg], stdev);
        ((float4*)(out + A))[ai] = d;
    }
    __syncthreads();
    if (tid < G && s_key[tid] != 0ULL) atomicMax(&gkey[tid], s_key[tid]);
    if (tid == 0 && s_cnt > 0) atomicAdd(cnt, s_cnt);
    __threadfence();
    if (tid == 0) {
        unsigned prev = atomicAdd(done, 1u);
        s_islast = (prev == gridDim.x - 1);
        s_cnt = 0;
    }
    __syncthreads();
    if (!s_islast) return;
    __threadfence();
    if (tid < G && s_crowdf[tid] == 0.0f) {
        unsigned long long key = gkey[tid];
        int w;
        if (key != 0ULL) w = (int)(~(unsigned)(key & 0xFFFFFFFFull));
        else { w = 0; for (int i = 0; i < A; ++i) { if (valid[i] != 0) { w = i; break; } } }
        if (valid[w] != 0) {
            float old = atomicExch(out + w, 1.0f);
            if (old != 1.0f) {
                float4 ab2 = anchors[w];
                float a2 = (ab2.z - ab2.x) * (ab2.w - ab2.y);
                float b2 = -2.0f; int g2 = 0;
                for (int g = 0; g < G; ++g) {
                    float iou = iou_of(ab2, a2, s_gt[g]);
                    float eff = (s_crowdf[g] != 0.0f) ? -1.0f : iou;
                    if (eff > b2) { b2 = eff; g2 = g; }
                }
                ((float4*)(out + A))[w] = compute_deltas(ab2, s_gt[g2], stdev);
                atomicAdd(&s_cnt, 1);
            }
        }
    }
    __syncthreads();
    if (tid == 0) out[(size_t)5 * A] = (float)(*cnt + s_cnt);
}

extern "C" void kernel_launch(void* const* d_in, const int* in_sizes, int n_in,
                              void* d_out, int out_size, void* d_ws, size_t ws_size,
                              hipStream_t stream) {
    const float4* anchors = (const float4*)d_in[0];
    const int* valid      = (const int*)d_in[1];   // jnp bool -> int32 per element
    const int* cls        = (const int*)d_in[2];
    const float4* gt      = (const float4*)d_in[3];
    const float* stdev    = (const float*)d_in[4];
    float* out            = (float*)d_out;

    const int A = in_sizes[0] / 4;
    const int G = in_sizes[2];                     // 256
    const int nch = (A + 511) / 512;               // 512 chunks
    const int nbp = 2 * nch;                       // 1024 pair blocks

    const size_t akey_bytes  = (size_t)2 * A * 8;
    const size_t cmax_bytes  = (size_t)2 * A * 4;
    const size_t shard_bytes = (size_t)G * SHARDS * 8;
    const size_t flag_bytes  = (size_t)nch * 4;
    const size_t pcnt_bytes  = (size_t)nch * 4;
    const size_t needed = akey_bytes + cmax_bytes + shard_bytes + flag_bytes + pcnt_bytes;

    if (ws_size >= needed && G <= GMAX) {
        char* p = (char*)d_ws;
        unsigned long long* akey  = (unsigned long long*)p;          p += akey_bytes;
        unsigned* cmaxA           = (unsigned*)p;                    p += cmax_bytes;
        unsigned long long* gkeyS = (unsigned long long*)p;          p += shard_bytes;
        unsigned* chunkdone       = (unsigned*)p;                    p += flag_bytes;
        int* pcount               = (int*)p;

        rpn_pairs3<<<nbp, 256, 0, stream>>>(anchors, valid, cls, gt, stdev, out,
                                            akey, cmaxA, gkeyS, chunkdone, pcount,
                                            A, G);
        rpn_finalize<<<1, 256, 0, stream>>>(anchors, valid, cls, gt, stdev, out,
                                            gkeyS, pcount, nch, A, G);
    } else {
        const int nb = (A + 255) / 256;
        unsigned long long* gkey = (unsigned long long*)d_ws;
        unsigned* done = (unsigned*)((char*)d_ws + 2048);
        int* cnt       = (int*)((char*)d_ws + 2052);
        hipMemsetAsync(d_ws, 0, 2056, stream);
        rpn_fused<<<nb, 256, 0, stream>>>(anchors, valid, cls, gt, stdev, out,
                                          gkey, done, cnt, A, G);
    }
}

// Round 10
// 149.745 us; speedup vs baseline: 1.5754x; 1.5754x over previous
//
#include <hip/hip_runtime.h>

// RPN target generation for MI355X — 3-node pipeline: pairs (G-split) -> merge -> finalize.
// Outputs (float32, concat): [0,A) rpn_match; [A,5A) rpn_bbox (A x 4); [5A] num_positives.
//
// Calibrated lessons (R2-R9):
//  * same-address device atomics ~100ns/op, NON-pipelining -> never O(grid) on one addr.
//  * DS queue is in-order -> no per-iter LDS atomics/shuffles in the hot loop;
//    per-lane VGPR bitmask + sparse post-loop drain (R5).
//  * best hot loop = G-split halves + 2 anchors/thread, 1024 blocks (R7: 54.5us, 78% VALU).
//  * single-block streaming of O(MB) ws = latency trap (R8: 103us) -> finalize reads
//    only 64KB, staged into LDS with coalesced loads.
//  * per-block __threadfence() = L2 writeback/invalidate on multi-XCD gfx950 (R9:
//    +100us) -> cross-block visibility ONLY via kernel boundaries.
//  * no memsets: gt-shard keys biased +0xC0000001 beat 0xAA ws poison under atomicMax.
//
// ws layout: [0,2A*8) akey | [+2A*4) cmaxA (crowd only) | [+G*32*8) gkeyS | [+nb*4) pcount

#define GMAX 256
#define SHARDS 32
#define KBIAS 0xC0000001u   // real key top-words in [0xC0000002, 0xFF800001]; poison 0xAAAA... loses

// Faithful to the reference, including the intentional size "bug":
// gt_size = y2 + y1 (not y2 - y1); centre = 0.5 * (y1 + y2).
__device__ __forceinline__ float4 compute_deltas(float4 ab, float4 gb,
                                                 const float* __restrict__ sd) {
    float sy_g = gb.z + gb.x;   // box = (y1, x1, y2, x2) in (x,y,z,w)
    float sx_g = gb.w + gb.y;
    float sy_a = ab.z + ab.x;
    float sx_a = ab.w + ab.y;
    float4 d;
    d.x = (0.5f * (sy_g - sy_a) / sy_a) / sd[0];
    d.y = (0.5f * (sx_g - sx_a) / sx_a) / sd[1];
    d.z = logf(sy_g / sy_a) / sd[2];
    d.w = logf(sx_g / sx_a) / sd[3];
    return d;
}

__device__ __forceinline__ float iou_of(float4 ab, float a_area, float4 gb) {
    float y1 = fmaxf(ab.x, gb.x);
    float x1 = fmaxf(ab.y, gb.y);
    float y2 = fminf(ab.z, gb.z);
    float x2 = fminf(ab.w, gb.w);
    float inter = fmaxf(y2 - y1, 0.f) * fmaxf(x2 - x1, 0.f);
    float garea = (gb.z - gb.x) * (gb.w - gb.y);
    float uni = (a_area + garea) - inter;
    return inter * __builtin_amdgcn_rcpf(uni);   // exact 0 if inter==0
}

// ---------- kernel 1: pair sweep, 2 anchors/thread, one G-half/block (R7 hot loop) ----------
__global__ __launch_bounds__(256) void rpn_pairs2(
    const float4* __restrict__ anchors,       // [A]
    const int* __restrict__ valid,            // [A] jnp bool as int32
    const int* __restrict__ cls,              // [G]
    const float4* __restrict__ gt,            // [G]
    unsigned long long* __restrict__ akey,    // [2*A] plain stores
    unsigned* __restrict__ cmaxA,             // [2*A] (crowd only)
    unsigned long long* __restrict__ gkeyS,   // [G*SHARDS] biased keys, poison-ok
    int A, int G)
{
    __shared__ float4 s_gt[GMAX / 2];
    __shared__ float s_crowdf[GMAX / 2];
    __shared__ unsigned long long s_key[GMAX / 2];
    __shared__ int s_anycrowd;

    const int tid = threadIdx.x;
    const int bi = blockIdx.x;
    const int half = bi & 1;
    const int chunk = bi >> 1;
    const int Gh = (G + 1) >> 1;
    const int g0 = half * Gh;
    const int gn = min(G - g0, Gh);           // 128 for G=256

    if (tid == 0) s_anycrowd = 0;
    if (tid < G && cls[tid] < 0) s_anycrowd = 1;   // any_crowd over FULL G
    if (tid < gn) {
        s_gt[tid] = gt[g0 + tid];
        s_crowdf[tid] = (cls[g0 + tid] < 0) ? 1.0f : 0.0f;
        s_key[tid] = 0ULL;
    }
    __syncthreads();
    const int any_crowd = s_anycrowd;

    const int ai0 = chunk * 512 + tid;
    const int ai1 = ai0 + 256;
    const bool ir0 = (ai0 < A), ir1 = (ai1 < A);
    float4 a0 = ir0 ? anchors[ai0] : make_float4(0.f, 0.f, 1.f, 1.f);
    float4 a1 = ir1 ? anchors[ai1] : make_float4(0.f, 0.f, 1.f, 1.f);
    const bool v0 = ir0 && (valid[ai0] != 0);
    const bool v1 = ir1 && (valid[ai1] != 0);
    const float ar0 = (a0.z - a0.x) * (a0.w - a0.y);
    const float ar1 = (a1.z - a1.x) * (a1.w - a1.y);

    float b0v, b1v;
    int bg0 = g0, bg1 = g0;
    float cm0 = 0.0f, cm1 = 0.0f;
    unsigned long long m00 = 0ULL, m01 = 0ULL, m10 = 0ULL, m11 = 0ULL;

    if (!any_crowd && gn == 128) {
        b0v = -1.0f; b1v = -1.0f;
        #pragma unroll
        for (int w = 0; w < 2; ++w) {
            unsigned long long ma = 0ULL, mb = 0ULL;
            #pragma unroll 4
            for (int j = 0; j < 64; ++j) {
                int gg = (w << 6) + j;
                float4 gb = s_gt[gg];          // one ds_read_b128 feeds 2 anchors
                float garea = (gb.z - gb.x) * (gb.w - gb.y);
                {
                    float y1 = fmaxf(a0.x, gb.x), x1 = fmaxf(a0.y, gb.y);
                    float y2 = fminf(a0.z, gb.z), x2 = fminf(a0.w, gb.w);
                    float inter = fmaxf(y2 - y1, 0.f) * fmaxf(x2 - x1, 0.f);
                    float iou = inter * __builtin_amdgcn_rcpf((ar0 + garea) - inter);
                    if (iou > b0v) { b0v = iou; bg0 = g0 + gg; }
                    if (iou > 0.0f) ma |= (1ULL << j);
                }
                {
                    float y1 = fmaxf(a1.x, gb.x), x1 = fmaxf(a1.y, gb.y);
                    float y2 = fminf(a1.z, gb.z), x2 = fminf(a1.w, gb.w);
                    float inter = fmaxf(y2 - y1, 0.f) * fmaxf(x2 - x1, 0.f);
                    float iou = inter * __builtin_amdgcn_rcpf((ar1 + garea) - inter);
                    if (iou > b1v) { b1v = iou; bg1 = g0 + gg; }
                    if (iou > 0.0f) mb |= (1ULL << j);
                }
            }
            if (w == 0) { m00 = ma; m10 = mb; } else { m01 = ma; m11 = mb; }
        }
    } else {
        // general path: crowd / odd sizes (correctness-only)
        b0v = -2.0f; b1v = -2.0f;
        for (int gg = 0; gg < gn; ++gg) {
            float4 gb = s_gt[gg];
            float cf = s_crowdf[gg];
            float i0 = iou_of(a0, ar0, gb);
            float i1 = iou_of(a1, ar1, gb);
            float e0 = (cf != 0.0f) ? -1.0f : i0;
            float e1 = (cf != 0.0f) ? -1.0f : i1;
            if (e0 > b0v) { b0v = e0; bg0 = g0 + gg; }
            if (e1 > b1v) { b1v = e1; bg1 = g0 + gg; }
            cm0 = fmaxf(cm0, i0 * cf);
            cm1 = fmaxf(cm1, i1 * cf);
            if (cf == 0.0f) {
                if (i0 > 0.0f) { if (gg < 64) m00 |= (1ULL << gg); else m01 |= (1ULL << (gg - 64)); }
                if (i1 > 0.0f) { if (gg < 64) m10 |= (1ULL << gg); else m11 |= (1ULL << (gg - 64)); }
            }
        }
    }

    if (ir0) {
        akey[(size_t)half * A + ai0] =
            (((unsigned long long)__float_as_uint(b0v)) << 32) | (unsigned)bg0;
        if (any_crowd) cmaxA[(size_t)half * A + ai0] = __float_as_uint(cm0);
    }
    if (ir1) {
        akey[(size_t)half * A + ai1] =
            (((unsigned long long)__float_as_uint(b1v)) << 32) | (unsigned)bg1;
        if (any_crowd) cmaxA[(size_t)half * A + ai1] = __float_as_uint(cm1);
    }

    // ---- sparse drain (~2-3 bits/lane/anchor): rare LDS atomicMax ----
    if (v0) {
        const unsigned lokey = ~(unsigned)ai0;   // smaller ai -> larger lokey
        #pragma unroll
        for (int w = 0; w < 2; ++w) {
            unsigned long long m = (w == 0) ? m00 : m01;
            while (m != 0ULL) {
                int j = __builtin_ctzll(m); m &= (m - 1ULL);
                int gg = (w << 6) + j;
                float iou = iou_of(a0, ar0, s_gt[gg]);
                atomicMax(&s_key[gg],
                    (((unsigned long long)(__float_as_uint(iou) + KBIAS)) << 32) | lokey);
            }
        }
    }
    if (v1) {
        const unsigned lokey = ~(unsigned)ai1;
        #pragma unroll
        for (int w = 0; w < 2; ++w) {
            unsigned long long m = (w == 0) ? m10 : m11;
            while (m != 0ULL) {
                int j = __builtin_ctzll(m); m &= (m - 1ULL);
                int gg = (w << 6) + j;
                float iou = iou_of(a1, ar1, s_gt[gg]);
                atomicMax(&s_key[gg],
                    (((unsigned long long)(__float_as_uint(iou) + KBIAS)) << 32) | lokey);
            }
        }
    }
    __syncthreads();

    // sharded global merge: ~16-way contention over G*SHARDS addresses;
    // biased keys always beat 0xAA poison, so no memset node needed.
    if (tid < gn && s_key[tid] != 0ULL)
        atomicMax(&gkeyS[(size_t)(g0 + tid) * SHARDS + (chunk & (SHARDS - 1))],
                  s_key[tid]);
}

// ---------- kernel 2: merge halves, write match/bbox, plain-store counts ----------
__global__ __launch_bounds__(256) void rpn_merge(
    const float4* __restrict__ anchors,
    const int* __restrict__ valid,
    const int* __restrict__ cls,
    const float4* __restrict__ gt,
    const float* __restrict__ stdev,
    float* __restrict__ out,
    const unsigned long long* __restrict__ akey,
    const unsigned* __restrict__ cmaxA,
    int* __restrict__ pcount,                  // [gridDim.x], plain stores
    int A, int G)
{
    __shared__ float4 s_gt[GMAX];
    __shared__ int s_anycrowd;
    __shared__ int s_cnt;

    const int tid = threadIdx.x;
    if (tid == 0) { s_anycrowd = 0; s_cnt = 0; }
    if (tid < G) {
        s_gt[tid] = gt[tid];
        if (cls[tid] < 0) s_anycrowd = 1;
    }
    __syncthreads();
    const int any_crowd = s_anycrowd;

    const int ai = blockIdx.x * 256 + tid;
    bool posv = false;
    if (ai < A) {
        unsigned long long k0 = akey[ai];
        unsigned long long k1 = akey[(size_t)A + ai];
        float bb0 = __uint_as_float((unsigned)(k0 >> 32));
        float bb1 = __uint_as_float((unsigned)(k1 >> 32));
        unsigned g_0 = (unsigned)k0, g_1 = (unsigned)k1;
        float best; int bg;
        if (bb1 > bb0 || (bb1 == bb0 && g_1 < g_0)) { best = bb1; bg = (int)g_1; }
        else                                        { best = bb0; bg = (int)g_0; }

        const bool v = (valid[ai] != 0);
        bool no_crowd = true;
        if (any_crowd)
            no_crowd = (fmaxf(__uint_as_float(cmaxA[ai]),
                              __uint_as_float(cmaxA[(size_t)A + ai])) < 0.001f);
        bool pos = (best >= 0.7f);
        bool neg = (best < 0.3f) && no_crowd && !pos;
        posv = pos && v;

        out[ai] = v ? (pos ? 1.0f : (neg ? -1.0f : 0.0f)) : 0.0f;
        float4 d = make_float4(0.f, 0.f, 0.f, 0.f);
        if (posv) d = compute_deltas(anchors[ai], s_gt[bg], stdev);
        ((float4*)(out + A))[ai] = d;
    }

    unsigned long long pv = __ballot((int)posv);
    if ((tid & 63) == 0) atomicAdd(&s_cnt, (int)__popcll(pv));   // LDS only
    __syncthreads();
    if (tid == 0) pcount[blockIdx.x] = s_cnt;                    // PLAIN store
}

// ---------- kernel 3: single-block finalize (64 KB, LDS-staged coalesced) ----------
__global__ __launch_bounds__(256) void rpn_finalize(
    const float4* __restrict__ anchors,
    const int* __restrict__ valid,
    const int* __restrict__ cls,
    const float4* __restrict__ gt,
    const float* __restrict__ stdev,
    float* __restrict__ out,
    const unsigned long long* __restrict__ gkeyS,
    const int* __restrict__ pcount,
    int nb, int A, int G)
{
    __shared__ float4 s_gt[GMAX];
    __shared__ float s_crowdf[GMAX];
    __shared__ unsigned long long s_keys[GMAX * SHARDS];   // 64 KB
    __shared__ int s_tot[256];
    __shared__ int s_cnt;

    const int tid = threadIdx.x;
    if (tid == 0) s_cnt = 0;
    if (tid < G) {
        s_gt[tid] = gt[tid];
        s_crowdf[tid] = (cls[tid] < 0) ? 1.0f : 0.0f;
    }

    // coalesced stage-in of the whole shard matrix (G*SHARDS u64)
    const int total = G * SHARDS;
    for (int i = tid; i < total; i += 256) s_keys[i] = gkeyS[i];

    // sum per-block positive counts (coalesced)
    int acc = 0;
    for (int i = tid; i < nb; i += 256) acc += pcount[i];
    s_tot[tid] = acc;
    __syncthreads();
    for (int s = 128; s > 0; s >>= 1) {
        if (tid < s) s_tot[tid] += s_tot[tid + s];
        __syncthreads();
    }

    if (tid < G && s_crowdf[tid] == 0.0f) {    // scatter value is False for crowd gts
        unsigned long long key = 0ULL;
        #pragma unroll
        for (int s = 0; s < SHARDS; ++s) {
            unsigned long long k = s_keys[tid * SHARDS + s];
            if (k > key) key = k;
        }
        const bool has = ((unsigned)(key >> 32) >= (KBIAS + 1u));  // poison/0 -> none
        int w;
        if (has) {
            w = (int)(~(unsigned)(key & 0xFFFFFFFFull));
        } else {
            // no valid anchor overlapped this gt: first valid anchor, else 0
            w = 0;
            for (int i = 0; i < A; ++i) { if (valid[i] != 0) { w = i; break; } }
        }
        if (valid[w] != 0) {
            float old = atomicExch(out + w, 1.0f);   // <=256 ops, mostly distinct
            if (old != 1.0f) {
                float4 ab2 = anchors[w];
                float a2 = (ab2.z - ab2.x) * (ab2.w - ab2.y);
                float b2 = -2.0f; int g2 = 0;
                for (int g = 0; g < G; ++g) {
                    float iou = iou_of(ab2, a2, s_gt[g]);
                    float eff = (s_crowdf[g] != 0.0f) ? -1.0f : iou;
                    if (eff > b2) { b2 = eff; g2 = g; }
                }
                ((float4*)(out + A))[w] = compute_deltas(ab2, s_gt[g2], stdev);
                atomicAdd(&s_cnt, 1);
            }
        }
    }
    __syncthreads();
    if (tid == 0) out[(size_t)5 * A] = (float)(s_tot[0] + s_cnt);
}

// ---------------- fallback: monolithic kernel (used only if ws too small) ------
__global__ __launch_bounds__(256) void rpn_fused(
    const float4* __restrict__ anchors, const int* __restrict__ valid,
    const int* __restrict__ cls, const float4* __restrict__ gt,
    const float* __restrict__ stdev, float* __restrict__ out,
    unsigned long long* __restrict__ gkey, unsigned* __restrict__ done,
    int* __restrict__ cnt, int A, int G)
{
    __shared__ float4 s_gt[GMAX];
    __shared__ float s_crowdf[GMAX];
    __shared__ unsigned long long s_key[GMAX];
    __shared__ int s_anycrowd; __shared__ int s_cnt; __shared__ int s_islast;

    const int tid = threadIdx.x;
    if (tid == 0) { s_anycrowd = 0; s_cnt = 0; }
    if (tid < G) {
        s_gt[tid] = gt[tid];
        int c = cls[tid];
        s_crowdf[tid] = (c < 0) ? 1.0f : 0.0f;
        if (c < 0) s_anycrowd = 1;
        s_key[tid] = 0ULL;
    }
    __syncthreads();
    const int any_crowd = s_anycrowd;
    const int ai = blockIdx.x * 256 + tid;
    const bool in_range = (ai < A);
    float4 ab = in_range ? anchors[ai] : make_float4(0.f, 0.f, 1.f, 1.f);
    const bool v = in_range && (valid[ai] != 0);
    const float a_area = (ab.z - ab.x) * (ab.w - ab.y);
    const unsigned lokey = ~(unsigned)ai;

    float best = any_crowd ? -2.0f : -1.0f;
    int bg = 0; float crowd_max = 0.0f;
    unsigned long long ovmask[4];
    #pragma unroll
    for (int w = 0; w < 4; ++w) {
        unsigned long long m = 0ULL;
        #pragma unroll 4
        for (int j = 0; j < 64; ++j) {
            int g = (w << 6) + j;
            if (g >= G) break;
            float iou = iou_of(ab, a_area, s_gt[g]);
            float cf = s_crowdf[g];
            float eff = (any_crowd && cf != 0.0f) ? -1.0f : iou;
            if (eff > best) { best = eff; bg = g; }
            if (any_crowd) crowd_max = fmaxf(crowd_max, iou * cf);
            if (v && (cf == 0.0f) && iou > 0.0f) m |= (1ULL << j);
        }
        ovmask[w] = m;
    }
    #pragma unroll
    for (int w = 0; w < 4; ++w) {
        unsigned long long m = ovmask[w];
        while (m != 0ULL) {
            int j = __builtin_ctzll(m); m &= (m - 1ULL);
            int g = (w << 6) + j;
            float iou = iou_of(ab, a_area, s_gt[g]);
            atomicMax(&s_key[g],
                (((unsigned long long)(__float_as_uint(iou) + 1u)) << 32) | lokey);
        }
    }
    bool no_crowd = any_crowd ? (crowd_max < 0.001f) : true;
    bool pos = (best >= 0.7f);
    bool neg = (best < 0.3f) && no_crowd && !pos;
    unsigned long long pv = __ballot((int)(in_range && pos && v));
    if ((tid & 63) == 0) atomicAdd(&s_cnt, (int)__popcll(pv));
    if (in_range) {
        out[ai] = v ? (pos ? 1.0f : (neg ? -1.0f : 0.0f)) : 0.0f;
        float4 d = make_float4(0.f, 0.f, 0.f, 0.f);
        if (pos && v) d = compute_deltas(ab, s_gt[bg], stdev);
        ((float4*)(out + A))[ai] = d;
    }
    __syncthreads();
    if (tid < G && s_key[tid] != 0ULL) atomicMax(&gkey[tid], s_key[tid]);
    if (tid == 0 && s_cnt > 0) atomicAdd(cnt, s_cnt);
    __threadfence();
    if (tid == 0) {
        unsigned prev = atomicAdd(done, 1u);
        s_islast = (prev == gridDim.x - 1);
        s_cnt = 0;
    }
    __syncthreads();
    if (!s_islast) return;
    __threadfence();
    if (tid < G && s_crowdf[tid] == 0.0f) {
        unsigned long long key = gkey[tid];
        int w;
        if (key != 0ULL) w = (int)(~(unsigned)(key & 0xFFFFFFFFull));
        else { w = 0; for (int i = 0; i < A; ++i) { if (valid[i] != 0) { w = i; break; } } }
        if (valid[w] != 0) {
            float old = atomicExch(out + w, 1.0f);
            if (old != 1.0f) {
                float4 ab2 = anchors[w];
                float a2 = (ab2.z - ab2.x) * (ab2.w - ab2.y);
                float b2 = -2.0f; int g2 = 0;
                for (int g = 0; g < G; ++g) {
                    float iou = iou_of(ab2, a2, s_gt[g]);
                    float eff = (s_crowdf[g] != 0.0f) ? -1.0f : iou;
                    if (eff > b2) { b2 = eff; g2 = g; }
                }
                ((float4*)(out + A))[w] = compute_deltas(ab2, s_gt[g2], stdev);
                atomicAdd(&s_cnt, 1);
            }
        }
    }
    __syncthreads();
    if (tid == 0) out[(size_t)5 * A] = (float)(*cnt + s_cnt);
}

extern "C" void kernel_launch(void* const* d_in, const int* in_sizes, int n_in,
                              void* d_out, int out_size, void* d_ws, size_t ws_size,
                              hipStream_t stream) {
    const float4* anchors = (const float4*)d_in[0];
    const int* valid      = (const int*)d_in[1];   // jnp bool -> int32 per element
    const int* cls        = (const int*)d_in[2];
    const float4* gt      = (const float4*)d_in[3];
    const float* stdev    = (const float*)d_in[4];
    float* out            = (float*)d_out;

    const int A = in_sizes[0] / 4;
    const int G = in_sizes[2];                     // 256
    const int nb = (A + 255) / 256;                // 1023 merge blocks
    const int nch = (A + 511) / 512;               // 512 chunks
    const int nbp = 2 * nch;                       // 1024 pair blocks

    const size_t akey_bytes  = (size_t)2 * A * 8;
    const size_t cmax_bytes  = (size_t)2 * A * 4;
    const size_t shard_bytes = (size_t)G * SHARDS * 8;
    const size_t pcnt_bytes  = (size_t)nb * 4;
    const size_t needed = akey_bytes + cmax_bytes + shard_bytes + pcnt_bytes;

    if (ws_size >= needed && G <= GMAX) {
        char* p = (char*)d_ws;
        unsigned long long* akey  = (unsigned long long*)p;          p += akey_bytes;
        unsigned* cmaxA           = (unsigned*)p;                    p += cmax_bytes;
        unsigned long long* gkeyS = (unsigned long long*)p;          p += shard_bytes;
        int* pcount               = (int*)p;

        rpn_pairs2<<<nbp, 256, 0, stream>>>(anchors, valid, cls, gt,
                                            akey, cmaxA, gkeyS, A, G);
        rpn_merge<<<nb, 256, 0, stream>>>(anchors, valid, cls, gt, stdev, out,
                                          akey, cmaxA, pcount, A, G);
        rpn_finalize<<<1, 256, 0, stream>>>(anchors, valid, cls, gt, stdev, out,
                                            gkeyS, pcount, nb, A, G);
    } else {
        unsigned long long* gkey = (unsigned long long*)d_ws;
        unsigned* done = (unsigned*)((char*)d_ws + 2048);
        int* cnt       = (int*)((char*)d_ws + 2052);
        hipMemsetAsync(d_ws, 0, 2056, stream);
        rpn_fused<<<nb, 256, 0, stream>>>(anchors, valid, cls, gt, stdev, out,
                                          gkey, done, cnt, A, G);
    }
}

// Round 11
// 134.151 us; speedup vs baseline: 1.7585x; 1.1162x over previous
//
#include <hip/hip_runtime.h>

// RPN target generation for MI355X — 2-node pipeline: full-G main -> tiny finalize.
// Outputs (float32, concat): [0,A) rpn_match; [A,5A) rpn_bbox (A x 4); [5A] num_positives.
//
// Calibrated lessons (R2-R10):
//  * same-address device atomics ~100ns/op, serialized per address -> depth must be O(32).
//  * DS queue in-order -> per-lane VGPR bitmask in hot loop + sparse post-loop LDS drain.
//  * per-block __threadfence() = L2 writeback on multi-XCD gfx950 (R9 +100us) ->
//    cross-block visibility ONLY via kernel boundaries.
//  * single-block streaming of O(MB) = latency trap (R8 103us) -> finalize reads 72KB.
//  * ~20us/graph-node fixed cost -> 2 nodes; no memsets (biased keys beat 0xAA poison;
//    pcount/fvmin/akey fully overwritten every launch).
//  * full-G main (vs G-split pairs) trades +20us DS (hidden under 60us VALU floor)
//    for deleting the merge node + akey round-trip; deltas for flipped winners use
//    the anchor's OWN argmax (reference semantics) -> finalize just reads akey[w].
//
// ws layout: [0,A*8) akey | [+G*32*8) gkeyS | [+nb*4) pcount | [+nb*4) fvmin

#define GMAX 256
#define SHARDS 32
#define KBIAS 0xC0000001u   // real key top-words >= 0xC0000002; 0xAAAAAAAA poison loses

// Faithful to the reference, including the intentional size "bug":
// gt_size = y2 + y1 (not y2 - y1); centre = 0.5 * (y1 + y2).
__device__ __forceinline__ float4 compute_deltas(float4 ab, float4 gb,
                                                 const float* __restrict__ sd) {
    float sy_g = gb.z + gb.x;   // box = (y1, x1, y2, x2) in (x,y,z,w)
    float sx_g = gb.w + gb.y;
    float sy_a = ab.z + ab.x;
    float sx_a = ab.w + ab.y;
    float4 d;
    d.x = (0.5f * (sy_g - sy_a) / sy_a) / sd[0];
    d.y = (0.5f * (sx_g - sx_a) / sx_a) / sd[1];
    d.z = logf(sy_g / sy_a) / sd[2];
    d.w = logf(sx_g / sx_a) / sd[3];
    return d;
}

__device__ __forceinline__ float iou_of(float4 ab, float a_area, float4 gb) {
    float y1 = fmaxf(ab.x, gb.x);
    float x1 = fmaxf(ab.y, gb.y);
    float y2 = fminf(ab.z, gb.z);
    float x2 = fminf(ab.w, gb.w);
    float inter = fmaxf(y2 - y1, 0.f) * fmaxf(x2 - x1, 0.f);
    float garea = (gb.z - gb.x) * (gb.w - gb.y);
    float uni = (a_area + garea) - inter;
    return inter * __builtin_amdgcn_rcpf(uni);   // exact 0 if inter==0
}

// ---------- kernel 1: full-G sweep, outputs + akey inline, sharded gt keys ----------
__global__ __launch_bounds__(256) void rpn_main2(
    const float4* __restrict__ anchors,       // [A]
    const int* __restrict__ valid,            // [A] jnp bool as int32
    const int* __restrict__ cls,              // [G]
    const float4* __restrict__ gt,            // [G]
    const float* __restrict__ stdev,          // [4]
    float* __restrict__ out,                  // [5A+1]
    unsigned long long* __restrict__ akey,    // [A] plain stores (best_bits:32|bg:32)
    unsigned long long* __restrict__ gkeyS,   // [G*SHARDS] biased keys, poison-ok
    int* __restrict__ pcount,                 // [nb] plain stores
    int* __restrict__ fvmin,                  // [nb] plain stores (min valid ai, else INT_MAX)
    int A, int G)
{
    __shared__ float4 s_gt[GMAX];
    __shared__ float s_crowdf[GMAX];
    __shared__ unsigned long long s_key[GMAX];
    __shared__ int s_anycrowd;
    __shared__ int s_cnt;
    __shared__ int s_fv;

    const int tid = threadIdx.x;
    if (tid == 0) { s_anycrowd = 0; s_cnt = 0; s_fv = 0x7FFFFFFF; }
    s_key[tid] = 0ULL;
    if (tid < G) {
        s_gt[tid] = gt[tid];
        int c = cls[tid];
        s_crowdf[tid] = (c < 0) ? 1.0f : 0.0f;
        if (c < 0) s_anycrowd = 1;            // benign race, same value
    }
    __syncthreads();
    const int any_crowd = s_anycrowd;

    const int ai = blockIdx.x * 256 + tid;
    const bool in_range = (ai < A);
    float4 ab = in_range ? anchors[ai] : make_float4(0.f, 0.f, 1.f, 1.f);
    const bool v = in_range && (valid[ai] != 0);
    const float a_area = (ab.z - ab.x) * (ab.w - ab.y);

    float best;
    int bg = 0;
    float crowd_max = 0.0f;
    unsigned long long m0 = 0ULL, m1 = 0ULL, m2 = 0ULL, m3 = 0ULL;

    if (!any_crowd && G == GMAX) {
        // ---- fast path ----
        best = -1.0f;
        #pragma unroll
        for (int w = 0; w < 4; ++w) {
            unsigned long long m = 0ULL;
            #pragma unroll 4
            for (int j = 0; j < 64; ++j) {
                int g = (w << 6) + j;
                float4 gb = s_gt[g];           // ds_read_b128, broadcast
                float y1 = fmaxf(ab.x, gb.x);
                float x1 = fmaxf(ab.y, gb.y);
                float y2 = fminf(ab.z, gb.z);
                float x2 = fminf(ab.w, gb.w);
                float inter = fmaxf(y2 - y1, 0.f) * fmaxf(x2 - x1, 0.f);
                float garea = (gb.z - gb.x) * (gb.w - gb.y);
                float iou = inter * __builtin_amdgcn_rcpf((a_area + garea) - inter);
                if (iou > best) { best = iou; bg = g; }        // first-index tie-break
                if (iou > 0.0f) m |= (1ULL << j);
            }
            if (w == 0) m0 = m; else if (w == 1) m1 = m; else if (w == 2) m2 = m; else m3 = m;
        }
    } else {
        // ---- general path: crowd / odd G (correctness-only) ----
        best = -2.0f;
        for (int g = 0; g < G; ++g) {
            float4 gb = s_gt[g];
            float iou = iou_of(ab, a_area, gb);
            float cf = s_crowdf[g];
            float eff = (cf != 0.0f) ? -1.0f : iou;
            if (eff > best) { best = eff; bg = g; }
            crowd_max = fmaxf(crowd_max, iou * cf);
            if (cf == 0.0f && iou > 0.0f) {
                int w = g >> 6, j = g & 63;
                if (w == 0) m0 |= (1ULL << j); else if (w == 1) m1 |= (1ULL << j);
                else if (w == 2) m2 |= (1ULL << j); else m3 |= (1ULL << j);
            }
        }
    }

    // ---- outputs: everything thread-local (full G) ----
    bool no_crowd = any_crowd ? (crowd_max < 0.001f) : true;
    bool pos = (best >= 0.7f);
    bool neg = (best < 0.3f) && no_crowd && !pos;
    bool posv = pos && v;

    if (in_range) {
        out[ai] = v ? (pos ? 1.0f : (neg ? -1.0f : 0.0f)) : 0.0f;
        float4 d = make_float4(0.f, 0.f, 0.f, 0.f);
        if (posv) d = compute_deltas(ab, s_gt[bg], stdev);
        ((float4*)(out + A))[ai] = d;
        akey[ai] = (((unsigned long long)__float_as_uint(best)) << 32) | (unsigned)bg;
    }

    // ---- sparse drain (~5 bits/lane): rare LDS atomicMax into s_key ----
    if (v) {
        const unsigned lokey = ~(unsigned)ai;   // smaller ai -> larger lokey
        atomicMin(&s_fv, ai);                   // block-local first valid anchor
        #pragma unroll
        for (int w = 0; w < 4; ++w) {
            unsigned long long m = (w == 0) ? m0 : (w == 1) ? m1 : (w == 2) ? m2 : m3;
            while (m != 0ULL) {
                int j = __builtin_ctzll(m); m &= (m - 1ULL);
                int g = (w << 6) + j;
                float iou = iou_of(ab, a_area, s_gt[g]);
                atomicMax(&s_key[g],
                    (((unsigned long long)(__float_as_uint(iou) + KBIAS)) << 32) | lokey);
            }
        }
    }

    unsigned long long pv = __ballot((int)posv);
    if ((tid & 63) == 0) atomicAdd(&s_cnt, (int)__popcll(pv));   // LDS only
    __syncthreads();

    // sharded global merge: ~32-deep per address over G*SHARDS addresses (calibrated ok);
    // biased keys beat 0xAA poison -> no memset node.
    if (tid < G && s_key[tid] != 0ULL)
        atomicMax(&gkeyS[(size_t)tid * SHARDS + (blockIdx.x & (SHARDS - 1))],
                  s_key[tid]);
    if (tid == 0) { pcount[blockIdx.x] = s_cnt; fvmin[blockIdx.x] = s_fv; }
}

// ---------- kernel 2: single-block finalize (72 KB reads, no recompute) ----------
__global__ __launch_bounds__(256) void rpn_finalize2(
    const float4* __restrict__ anchors,
    const int* __restrict__ valid,
    const int* __restrict__ cls,
    const float4* __restrict__ gt,
    const float* __restrict__ stdev,
    float* __restrict__ out,
    const unsigned long long* __restrict__ akey,
    const unsigned long long* __restrict__ gkeyS,
    const int* __restrict__ pcount,
    const int* __restrict__ fvmin,
    int nb, int A, int G)
{
    __shared__ float4 s_gt[GMAX];
    __shared__ float s_crowdf[GMAX];
    __shared__ unsigned long long s_red[GMAX];   // per-gt max key
    __shared__ int s_tot[256];
    __shared__ int s_fvt[256];
    __shared__ int s_cnt;

    const int tid = threadIdx.x;
    if (tid == 0) s_cnt = 0;
    s_red[tid] = 0ULL;
    if (tid < G) {
        s_gt[tid] = gt[tid];
        s_crowdf[tid] = (cls[tid] < 0) ? 1.0f : 0.0f;
    }
    __syncthreads();

    // reduce shard matrix (G*SHARDS u64, coalesced) into s_red via LDS atomics
    const int total = G * SHARDS;
    for (int i = tid; i < total; i += 256) {
        unsigned long long k = gkeyS[i];       // includes 0xAA poison: loses to real keys
        atomicMax(&s_red[i >> 5], k);          // SHARDS == 32
    }

    // sum pcount, min fvmin (coalesced)
    int acc = 0, fv = 0x7FFFFFFF;
    for (int i = tid; i < nb; i += 256) {
        acc += pcount[i];
        fv = min(fv, fvmin[i]);
    }
    s_tot[tid] = acc;
    s_fvt[tid] = fv;
    __syncthreads();
    for (int s = 128; s > 0; s >>= 1) {
        if (tid < s) {
            s_tot[tid] += s_tot[tid + s];
            s_fvt[tid] = min(s_fvt[tid], s_fvt[tid + s]);
        }
        __syncthreads();
    }
    const int first_valid = s_fvt[0];

    if (tid < G && s_crowdf[tid] == 0.0f) {    // scatter value is False for crowd gts
        unsigned long long key = s_red[tid];
        const bool has = ((unsigned)(key >> 32) >= (KBIAS + 1u));  // poison/empty -> none
        int w = -1;
        if (has) {
            w = (int)(~(unsigned)(key & 0xFFFFFFFFull));
        } else if (first_valid != 0x7FFFFFFF) {
            // no valid anchor overlapped this gt: column argmax = first valid anchor
            w = first_valid;
        }
        // w from keys is always a valid anchor (drain is valid-gated); fallback valid too.
        if (w >= 0) {
            float old = atomicExch(out + w, 1.0f);   // <=256 ops, mostly distinct addrs
            if (old != 1.0f) {
                // flipped to positive: deltas use the anchor's OWN argmax (akey[w])
                int bg = (int)(unsigned)akey[w];
                ((float4*)(out + A))[w] = compute_deltas(anchors[w], s_gt[bg], stdev);
                atomicAdd(&s_cnt, 1);
            }
        }
    }
    __syncthreads();
    if (tid == 0) out[(size_t)5 * A] = (float)(s_tot[0] + s_cnt);
}

// ---------------- fallback: monolithic kernel (used only if ws too small) ------
__global__ __launch_bounds__(256) void rpn_fused(
    const float4* __restrict__ anchors, const int* __restrict__ valid,
    const int* __restrict__ cls, const float4* __restrict__ gt,
    const float* __restrict__ stdev, float* __restrict__ out,
    unsigned long long* __restrict__ gkey, unsigned* __restrict__ done,
    int* __restrict__ cnt, int A, int G)
{
    __shared__ float4 s_gt[GMAX];
    __shared__ float s_crowdf[GMAX];
    __shared__ unsigned long long s_key[GMAX];
    __shared__ int s_anycrowd; __shared__ int s_cnt; __shared__ int s_islast;

    const int tid = threadIdx.x;
    if (tid == 0) { s_anycrowd = 0; s_cnt = 0; }
    if (tid < G) {
        s_gt[tid] = gt[tid];
        int c = cls[tid];
        s_crowdf[tid] = (c < 0) ? 1.0f : 0.0f;
        if (c < 0) s_anycrowd = 1;
        s_key[tid] = 0ULL;
    }
    __syncthreads();
    const int any_crowd = s_anycrowd;
    const int ai = blockIdx.x * 256 + tid;
    const bool in_range = (ai < A);
    float4 ab = in_range ? anchors[ai] : make_float4(0.f, 0.f, 1.f, 1.f);
    const bool v = in_range && (valid[ai] != 0);
    const float a_area = (ab.z - ab.x) * (ab.w - ab.y);
    const unsigned lokey = ~(unsigned)ai;

    float best = any_crowd ? -2.0f : -1.0f;
    int bg = 0; float crowd_max = 0.0f;
    unsigned long long ovmask[4];
    #pragma unroll
    for (int w = 0; w < 4; ++w) {
        unsigned long long m = 0ULL;
        #pragma unroll 4
        for (int j = 0; j < 64; ++j) {
            int g = (w << 6) + j;
            if (g >= G) break;
            float iou = iou_of(ab, a_area, s_gt[g]);
            float cf = s_crowdf[g];
            float eff = (any_crowd && cf != 0.0f) ? -1.0f : iou;
            if (eff > best) { best = eff; bg = g; }
            if (any_crowd) crowd_max = fmaxf(crowd_max, iou * cf);
            if (v && (cf == 0.0f) && iou > 0.0f) m |= (1ULL << j);
        }
        ovmask[w] = m;
    }
    #pragma unroll
    for (int w = 0; w < 4; ++w) {
        unsigned long long m = ovmask[w];
        while (m != 0ULL) {
            int j = __builtin_ctzll(m); m &= (m - 1ULL);
            int g = (w << 6) + j;
            float iou = iou_of(ab, a_area, s_gt[g]);
            atomicMax(&s_key[g],
                (((unsigned long long)(__float_as_uint(iou) + 1u)) << 32) | lokey);
        }
    }
    bool no_crowd = any_crowd ? (crowd_max < 0.001f) : true;
    bool pos = (best >= 0.7f);
    bool neg = (best < 0.3f) && no_crowd && !pos;
    unsigned long long pv = __ballot((int)(in_range && pos && v));
    if ((tid & 63) == 0) atomicAdd(&s_cnt, (int)__popcll(pv));
    if (in_range) {
        out[ai] = v ? (pos ? 1.0f : (neg ? -1.0f : 0.0f)) : 0.0f;
        float4 d = make_float4(0.f, 0.f, 0.f, 0.f);
        if (pos && v) d = compute_deltas(ab, s_gt[bg], stdev);
        ((float4*)(out + A))[ai] = d;
    }
    __syncthreads();
    if (tid < G && s_key[tid] != 0ULL) atomicMax(&gkey[tid], s_key[tid]);
    if (tid == 0 && s_cnt > 0) atomicAdd(cnt, s_cnt);
    __threadfence();
    if (tid == 0) {
        unsigned prev = atomicAdd(done, 1u);
        s_islast = (prev == gridDim.x - 1);
        s_cnt = 0;
    }
    __syncthreads();
    if (!s_islast) return;
    __threadfence();
    if (tid < G && s_crowdf[tid] == 0.0f) {
        unsigned long long key = gkey[tid];
        int w;
        if (key != 0ULL) w = (int)(~(unsigned)(key & 0xFFFFFFFFull));
        else { w = 0; for (int i = 0; i < A; ++i) { if (valid[i] != 0) { w = i; break; } } }
        if (valid[w] != 0) {
            float old = atomicExch(out + w, 1.0f);
            if (old != 1.0f) {
                float4 ab2 = anchors[w];
                float a2 = (ab2.z - ab2.x) * (ab2.w - ab2.y);
                float b2 = -2.0f; int g2 = 0;
                for (int g = 0; g < G; ++g) {
                    float iou = iou_of(ab2, a2, s_gt[g]);
                    float eff = (s_crowdf[g] != 0.0f) ? -1.0f : iou;
                    if (eff > b2) { b2 = eff; g2 = g; }
                }
                ((float4*)(out + A))[w] = compute_deltas(ab2, s_gt[g2], stdev);
                atomicAdd(&s_cnt, 1);
            }
        }
    }
    __syncthreads();
    if (tid == 0) out[(size_t)5 * A] = (float)(*cnt + s_cnt);
}

extern "C" void kernel_launch(void* const* d_in, const int* in_sizes, int n_in,
                              void* d_out, int out_size, void* d_ws, size_t ws_size,
                              hipStream_t stream) {
    const float4* anchors = (const float4*)d_in[0];
    const int* valid      = (const int*)d_in[1];   // jnp bool -> int32 per element
    const int* cls        = (const int*)d_in[2];
    const float4* gt      = (const float4*)d_in[3];
    const float* stdev    = (const float*)d_in[4];
    float* out            = (float*)d_out;

    const int A = in_sizes[0] / 4;
    const int G = in_sizes[2];                     // 256
    const int nb = (A + 255) / 256;                // 1023

    const size_t akey_bytes  = (size_t)A * 8;
    const size_t shard_bytes = (size_t)G * SHARDS * 8;
    const size_t pcnt_bytes  = (size_t)nb * 4;
    const size_t fv_bytes    = (size_t)nb * 4;
    const size_t needed = akey_bytes + shard_bytes + pcnt_bytes + fv_bytes;

    if (ws_size >= needed && G <= GMAX) {
        char* p = (char*)d_ws;
        unsigned long long* akey  = (unsigned long long*)p;          p += akey_bytes;
        unsigned long long* gkeyS = (unsigned long long*)p;          p += shard_bytes;
        int* pcount               = (int*)p;                         p += pcnt_bytes;
        int* fvmin                = (int*)p;

        rpn_main2<<<nb, 256, 0, stream>>>(anchors, valid, cls, gt, stdev, out,
                                          akey, gkeyS, pcount, fvmin, A, G);
        rpn_finalize2<<<1, 256, 0, stream>>>(anchors, valid, cls, gt, stdev, out,
                                             akey, gkeyS, pcount, fvmin, nb, A, G);
    } else {
        unsigned long long* gkey = (unsigned long long*)d_ws;
        unsigned* done = (unsigned*)((char*)d_ws + 2048);
        int* cnt       = (int*)((char*)d_ws + 2052);
        hipMemsetAsync(d_ws, 0, 2056, stream);
        rpn_fused<<<nb, 256, 0, stream>>>(anchors, valid, cls, gt, stdev, out,
                                          gkey, done, cnt, A, G);
    }
}

// Round 12
// 128.686 us; speedup vs baseline: 1.8332x; 1.0425x over previous
//
#include <hip/hip_runtime.h>

// RPN target generation for MI355X — 2-node pipeline: full-G main -> tiny finalize.
// Outputs (float32, concat): [0,A) rpn_match; [A,5A) rpn_bbox (A x 4); [5A] num_positives.
//
// Calibrated lessons (R2-R11):
//  * same-address device atomics ~100ns/op, serialized per address -> depth O(32) max.
//  * DS queue in-order -> per-lane VGPR bitmask in hot loop + sparse post-loop LDS drain.
//  * per-block __threadfence() = L2 writeback on multi-XCD gfx950 (R9 +100us) ->
//    cross-block visibility ONLY via kernel boundaries.
//  * single-block latency-streaming trap (R8) -> finalize reads 34KB with 1024 thr.
//  * no memsets: biased keys beat 0xAA poison; all other ws slots fully overwritten.
//  * main loop is VALU-issue-bound (R11: 85% busy) -> move per-gt invariants (area)
//    to LDS; DS pipe has ~25us slack under the ~55us VALU floor.
//
// ws layout: [0,A*8) akey | [+G*16*8) gkeyS | [+nb*4) pcount | [+nb*4) fvmin

#define GMAX 256
#define SHARDS 16
#define KBIAS 0xC0000001u   // real key top-words >= 0xC0000002; 0xAAAAAAAA poison loses

// Faithful to the reference, including the intentional size "bug":
// gt_size = y2 + y1 (not y2 - y1); centre = 0.5 * (y1 + y2).
__device__ __forceinline__ float4 compute_deltas(float4 ab, float4 gb,
                                                 const float* __restrict__ sd) {
    float sy_g = gb.z + gb.x;   // box = (y1, x1, y2, x2) in (x,y,z,w)
    float sx_g = gb.w + gb.y;
    float sy_a = ab.z + ab.x;
    float sx_a = ab.w + ab.y;
    float4 d;
    d.x = (0.5f * (sy_g - sy_a) / sy_a) / sd[0];
    d.y = (0.5f * (sx_g - sx_a) / sx_a) / sd[1];
    d.z = logf(sy_g / sy_a) / sd[2];
    d.w = logf(sx_g / sx_a) / sd[3];
    return d;
}

__device__ __forceinline__ float iou_of(float4 ab, float a_area, float4 gb) {
    float y1 = fmaxf(ab.x, gb.x);
    float x1 = fmaxf(ab.y, gb.y);
    float y2 = fminf(ab.z, gb.z);
    float x2 = fminf(ab.w, gb.w);
    float inter = fmaxf(y2 - y1, 0.f) * fmaxf(x2 - x1, 0.f);
    float garea = (gb.z - gb.x) * (gb.w - gb.y);
    float uni = (a_area + garea) - inter;
    return inter * __builtin_amdgcn_rcpf(uni);   // exact 0 if inter==0
}

// ---------- kernel 1: full-G sweep, outputs + akey inline, sharded gt keys ----------
__global__ __launch_bounds__(256) void rpn_main2(
    const float4* __restrict__ anchors,       // [A]
    const int* __restrict__ valid,            // [A] jnp bool as int32
    const int* __restrict__ cls,              // [G]
    const float4* __restrict__ gt,            // [G]
    const float* __restrict__ stdev,          // [4]
    float* __restrict__ out,                  // [5A+1]
    unsigned long long* __restrict__ akey,    // [A] plain stores (best_bits:32|bg:32)
    unsigned long long* __restrict__ gkeyS,   // [G*SHARDS] biased keys, poison-ok
    int* __restrict__ pcount,                 // [nb] plain stores
    int* __restrict__ fvmin,                  // [nb] plain stores (min valid ai, else INT_MAX)
    int A, int G)
{
    __shared__ float4 s_gt[GMAX];
    __shared__ float s_area[GMAX];            // per-gt area, loop-invariant (saves 3 VALU/iter)
    __shared__ float s_crowdf[GMAX];
    __shared__ unsigned long long s_key[GMAX];
    __shared__ int s_anycrowd;
    __shared__ int s_cnt;
    __shared__ int s_fv;

    const int tid = threadIdx.x;
    if (tid == 0) { s_anycrowd = 0; s_cnt = 0; s_fv = 0x7FFFFFFF; }
    s_key[tid] = 0ULL;
    if (tid < G) {
        float4 b = gt[tid];
        s_gt[tid] = b;
        s_area[tid] = (b.z - b.x) * (b.w - b.y);
        int c = cls[tid];
        s_crowdf[tid] = (c < 0) ? 1.0f : 0.0f;
        if (c < 0) s_anycrowd = 1;            // benign race, same value
    }
    __syncthreads();
    const int any_crowd = s_anycrowd;

    const int ai = blockIdx.x * 256 + tid;
    const bool in_range = (ai < A);
    float4 ab = in_range ? anchors[ai] : make_float4(0.f, 0.f, 1.f, 1.f);
    const bool v = in_range && (valid[ai] != 0);
    const float a_area = (ab.z - ab.x) * (ab.w - ab.y);

    float best;
    int bg = 0;
    float crowd_max = 0.0f;
    unsigned long long m0 = 0ULL, m1 = 0ULL, m2 = 0ULL, m3 = 0ULL;

    if (!any_crowd && G == GMAX) {
        // ---- fast path ----
        best = -1.0f;
        #pragma unroll
        for (int w = 0; w < 4; ++w) {
            unsigned long long m = 0ULL;
            #pragma unroll 4
            for (int j = 0; j < 64; ++j) {
                int g = (w << 6) + j;
                float4 gb = s_gt[g];           // ds_read_b128, broadcast
                float y1 = fmaxf(ab.x, gb.x);
                float x1 = fmaxf(ab.y, gb.y);
                float y2 = fminf(ab.z, gb.z);
                float x2 = fminf(ab.w, gb.w);
                float inter = fmaxf(y2 - y1, 0.f) * fmaxf(x2 - x1, 0.f);
                float iou = inter * __builtin_amdgcn_rcpf((a_area + s_area[g]) - inter);
                if (iou > best) { best = iou; bg = g; }        // first-index tie-break
                if (iou > 0.0f) m |= (1ULL << j);
            }
            if (w == 0) m0 = m; else if (w == 1) m1 = m; else if (w == 2) m2 = m; else m3 = m;
        }
        if (best == 0.0f) bg = 0;              // argmax of all-zero column block = 0
    } else {
        // ---- general path: crowd / odd G (correctness-only) ----
        best = -2.0f;
        for (int g = 0; g < G; ++g) {
            float4 gb = s_gt[g];
            float iou = iou_of(ab, a_area, gb);
            float cf = s_crowdf[g];
            float eff = (cf != 0.0f) ? -1.0f : iou;
            if (eff > best) { best = eff; bg = g; }
            crowd_max = fmaxf(crowd_max, iou * cf);
            if (cf == 0.0f && iou > 0.0f) {
                int w = g >> 6, j = g & 63;
                if (w == 0) m0 |= (1ULL << j); else if (w == 1) m1 |= (1ULL << j);
                else if (w == 2) m2 |= (1ULL << j); else m3 |= (1ULL << j);
            }
        }
    }

    // ---- outputs: everything thread-local (full G) ----
    bool no_crowd = any_crowd ? (crowd_max < 0.001f) : true;
    bool pos = (best >= 0.7f);
    bool neg = (best < 0.3f) && no_crowd && !pos;
    bool posv = pos && v;

    if (in_range) {
        out[ai] = v ? (pos ? 1.0f : (neg ? -1.0f : 0.0f)) : 0.0f;
        float4 d = make_float4(0.f, 0.f, 0.f, 0.f);
        if (posv) d = compute_deltas(ab, s_gt[bg], stdev);
        ((float4*)(out + A))[ai] = d;
        akey[ai] = (((unsigned long long)__float_as_uint(best)) << 32) | (unsigned)bg;
    }

    // ---- sparse drain (~5 bits/lane): rare LDS atomicMax into s_key ----
    if (v) {
        const unsigned lokey = ~(unsigned)ai;   // smaller ai -> larger lokey
        atomicMin(&s_fv, ai);                   // block-local first valid anchor
        #pragma unroll
        for (int w = 0; w < 4; ++w) {
            unsigned long long m = (w == 0) ? m0 : (w == 1) ? m1 : (w == 2) ? m2 : m3;
            while (m != 0ULL) {
                int j = __builtin_ctzll(m); m &= (m - 1ULL);
                int g = (w << 6) + j;
                float iou = iou_of(ab, a_area, s_gt[g]);
                atomicMax(&s_key[g],
                    (((unsigned long long)(__float_as_uint(iou) + KBIAS)) << 32) | lokey);
            }
        }
    }

    unsigned long long pv = __ballot((int)posv);
    if ((tid & 63) == 0) atomicAdd(&s_cnt, (int)__popcll(pv));   // LDS only
    __syncthreads();

    // sharded global merge: ~8-deep per address over G*SHARDS addresses;
    // biased keys beat 0xAA poison -> no memset node.
    if (tid < G && s_key[tid] != 0ULL)
        atomicMax(&gkeyS[(size_t)tid * SHARDS + (blockIdx.x & (SHARDS - 1))],
                  s_key[tid]);
    if (tid == 0) { pcount[blockIdx.x] = s_cnt; fvmin[blockIdx.x] = s_fv; }
}

// ---------- kernel 2: single-block finalize (1024 thr, 34 KB reads, no recompute) ----------
__global__ __launch_bounds__(1024) void rpn_finalize2(
    const float4* __restrict__ anchors,
    const int* __restrict__ valid,
    const int* __restrict__ cls,
    const float4* __restrict__ gt,
    const float* __restrict__ stdev,
    float* __restrict__ out,
    const unsigned long long* __restrict__ akey,
    const unsigned long long* __restrict__ gkeyS,
    const int* __restrict__ pcount,
    const int* __restrict__ fvmin,
    int nb, int A, int G)
{
    __shared__ float4 s_gt[GMAX];
    __shared__ float s_crowdf[GMAX];
    __shared__ unsigned long long s_red[GMAX];   // per-gt max key
    __shared__ int s_tot[1024];
    __shared__ int s_fvt[1024];
    __shared__ int s_cnt;

    const int tid = threadIdx.x;
    if (tid == 0) s_cnt = 0;
    if (tid < GMAX) s_red[tid] = 0ULL;
    if (tid < G) {
        s_gt[tid] = gt[tid];
        s_crowdf[tid] = (cls[tid] < 0) ? 1.0f : 0.0f;
    }
    __syncthreads();

    // reduce shard matrix (G*SHARDS u64, coalesced, 4 rounds) into s_red via LDS atomics
    const int total = G * SHARDS;
    for (int i = tid; i < total; i += 1024) {
        unsigned long long k = gkeyS[i];       // 0xAA poison loses to real biased keys
        atomicMax(&s_red[i / SHARDS], k);
    }

    // sum pcount, min fvmin (coalesced, 1 round)
    int acc = 0, fv = 0x7FFFFFFF;
    for (int i = tid; i < nb; i += 1024) {
        acc += pcount[i];
        fv = min(fv, fvmin[i]);
    }
    s_tot[tid] = acc;
    s_fvt[tid] = fv;
    __syncthreads();
    for (int s = 512; s > 0; s >>= 1) {
        if (tid < s) {
            s_tot[tid] += s_tot[tid + s];
            s_fvt[tid] = min(s_fvt[tid], s_fvt[tid + s]);
        }
        __syncthreads();
    }
    const int first_valid = s_fvt[0];

    if (tid < G && s_crowdf[tid] == 0.0f) {    // scatter value is False for crowd gts
        unsigned long long key = s_red[tid];
        const bool has = ((unsigned)(key >> 32) >= (KBIAS + 1u));  // poison/empty -> none
        int w = -1;
        if (has) {
            w = (int)(~(unsigned)(key & 0xFFFFFFFFull));
        } else if (first_valid != 0x7FFFFFFF) {
            // no valid anchor overlapped this gt: column argmax = first valid anchor
            w = first_valid;
        }
        if (w >= 0) {
            float old = atomicExch(out + w, 1.0f);   // <=256 ops, mostly distinct addrs
            if (old != 1.0f) {
                // flipped to positive: deltas use the anchor's OWN argmax (akey[w])
                int bg = (int)(unsigned)akey[w];
                ((float4*)(out + A))[w] = compute_deltas(anchors[w], s_gt[bg], stdev);
                atomicAdd(&s_cnt, 1);
            }
        }
    }
    __syncthreads();
    if (tid == 0) out[(size_t)5 * A] = (float)(s_tot[0] + s_cnt);
}

// ---------------- fallback: monolithic kernel (used only if ws too small) ------
__global__ __launch_bounds__(256) void rpn_fused(
    const float4* __restrict__ anchors, const int* __restrict__ valid,
    const int* __restrict__ cls, const float4* __restrict__ gt,
    const float* __restrict__ stdev, float* __restrict__ out,
    unsigned long long* __restrict__ gkey, unsigned* __restrict__ done,
    int* __restrict__ cnt, int A, int G)
{
    __shared__ float4 s_gt[GMAX];
    __shared__ float s_crowdf[GMAX];
    __shared__ unsigned long long s_key[GMAX];
    __shared__ int s_anycrowd; __shared__ int s_cnt; __shared__ int s_islast;

    const int tid = threadIdx.x;
    if (tid == 0) { s_anycrowd = 0; s_cnt = 0; }
    if (tid < G) {
        s_gt[tid] = gt[tid];
        int c = cls[tid];
        s_crowdf[tid] = (c < 0) ? 1.0f : 0.0f;
        if (c < 0) s_anycrowd = 1;
        s_key[tid] = 0ULL;
    }
    __syncthreads();
    const int any_crowd = s_anycrowd;
    const int ai = blockIdx.x * 256 + tid;
    const bool in_range = (ai < A);
    float4 ab = in_range ? anchors[ai] : make_float4(0.f, 0.f, 1.f, 1.f);
    const bool v = in_range && (valid[ai] != 0);
    const float a_area = (ab.z - ab.x) * (ab.w - ab.y);
    const unsigned lokey = ~(unsigned)ai;

    float best = any_crowd ? -2.0f : -1.0f;
    int bg = 0; float crowd_max = 0.0f;
    unsigned long long ovmask[4];
    #pragma unroll
    for (int w = 0; w < 4; ++w) {
        unsigned long long m = 0ULL;
        #pragma unroll 4
        for (int j = 0; j < 64; ++j) {
            int g = (w << 6) + j;
            if (g >= G) break;
            float iou = iou_of(ab, a_area, s_gt[g]);
            float cf = s_crowdf[g];
            float eff = (any_crowd && cf != 0.0f) ? -1.0f : iou;
            if (eff > best) { best = eff; bg = g; }
            if (any_crowd) crowd_max = fmaxf(crowd_max, iou * cf);
            if (v && (cf == 0.0f) && iou > 0.0f) m |= (1ULL << j);
        }
        ovmask[w] = m;
    }
    #pragma unroll
    for (int w = 0; w < 4; ++w) {
        unsigned long long m = ovmask[w];
        while (m != 0ULL) {
            int j = __builtin_ctzll(m); m &= (m - 1ULL);
            int g = (w << 6) + j;
            float iou = iou_of(ab, a_area, s_gt[g]);
            atomicMax(&s_key[g],
                (((unsigned long long)(__float_as_uint(iou) + 1u)) << 32) | lokey);
        }
    }
    bool no_crowd = any_crowd ? (crowd_max < 0.001f) : true;
    bool pos = (best >= 0.7f);
    bool neg = (best < 0.3f) && no_crowd && !pos;
    unsigned long long pv = __ballot((int)(in_range && pos && v));
    if ((tid & 63) == 0) atomicAdd(&s_cnt, (int)__popcll(pv));
    if (in_range) {
        out[ai] = v ? (pos ? 1.0f : (neg ? -1.0f : 0.0f)) : 0.0f;
        float4 d = make_float4(0.f, 0.f, 0.f, 0.f);
        if (pos && v) d = compute_deltas(ab, s_gt[bg], stdev);
        ((float4*)(out + A))[ai] = d;
    }
    __syncthreads();
    if (tid < G && s_key[tid] != 0ULL) atomicMax(&gkey[tid], s_key[tid]);
    if (tid == 0 && s_cnt > 0) atomicAdd(cnt, s_cnt);
    __threadfence();
    if (tid == 0) {
        unsigned prev = atomicAdd(done, 1u);
        s_islast = (prev == gridDim.x - 1);
        s_cnt = 0;
    }
    __syncthreads();
    if (!s_islast) return;
    __threadfence();
    if (tid < G && s_crowdf[tid] == 0.0f) {
        unsigned long long key = gkey[tid];
        int w;
        if (key != 0ULL) w = (int)(~(unsigned)(key & 0xFFFFFFFFull));
        else { w = 0; for (int i = 0; i < A; ++i) { if (valid[i] != 0) { w = i; break; } } }
        if (valid[w] != 0) {
            float old = atomicExch(out + w, 1.0f);
            if (old != 1.0f) {
                float4 ab2 = anchors[w];
                float a2 = (ab2.z - ab2.x) * (ab2.w - ab2.y);
                float b2 = -2.0f; int g2 = 0;
                for (int g = 0; g < G; ++g) {
                    float iou = iou_of(ab2, a2, s_gt[g]);
                    float eff = (s_crowdf[g] != 0.0f) ? -1.0f : iou;
                    if (eff > b2) { b2 = eff; g2 = g; }
                }
                ((float4*)(out + A))[w] = compute_deltas(ab2, s_gt[g2], stdev);
                atomicAdd(&s_cnt, 1);
            }
        }
    }
    __syncthreads();
    if (tid == 0) out[(size_t)5 * A] = (float)(*cnt + s_cnt);
}

extern "C" void kernel_launch(void* const* d_in, const int* in_sizes, int n_in,
                              void* d_out, int out_size, void* d_ws, size_t ws_size,
                              hipStream_t stream) {
    const float4* anchors = (const float4*)d_in[0];
    const int* valid      = (const int*)d_in[1];   // jnp bool -> int32 per element
    const int* cls        = (const int*)d_in[2];
    const float4* gt      = (const float4*)d_in[3];
    const float* stdev    = (const float*)d_in[4];
    float* out            = (float*)d_out;

    const int A = in_sizes[0] / 4;
    const int G = in_sizes[2];                     // 256
    const int nb = (A + 255) / 256;                // 1023

    const size_t akey_bytes  = (size_t)A * 8;
    const size_t shard_bytes = (size_t)G * SHARDS * 8;
    const size_t pcnt_bytes  = (size_t)nb * 4;
    const size_t fv_bytes    = (size_t)nb * 4;
    const size_t needed = akey_bytes + shard_bytes + pcnt_bytes + fv_bytes;

    if (ws_size >= needed && G <= GMAX) {
        char* p = (char*)d_ws;
        unsigned long long* akey  = (unsigned long long*)p;          p += akey_bytes;
        unsigned long long* gkeyS = (unsigned long long*)p;          p += shard_bytes;
        int* pcount               = (int*)p;                         p += pcnt_bytes;
        int* fvmin                = (int*)p;

        rpn_main2<<<nb, 256, 0, stream>>>(anchors, valid, cls, gt, stdev, out,
                                          akey, gkeyS, pcount, fvmin, A, G);
        rpn_finalize2<<<1, 1024, 0, stream>>>(anchors, valid, cls, gt, stdev, out,
                                              akey, gkeyS, pcount, fvmin, nb, A, G);
    } else {
        unsigned long long* gkey = (unsigned long long*)d_ws;
        unsigned* done = (unsigned*)((char*)d_ws + 2048);
        int* cnt       = (int*)((char*)d_ws + 2052);
        hipMemsetAsync(d_ws, 0, 2056, stream);
        rpn_fused<<<nb, 256, 0, stream>>>(anchors, valid, cls, gt, stdev, out,
                                          gkey, done, cnt, A, G);
    }
}

// Round 13
// 126.943 us; speedup vs baseline: 1.8584x; 1.0137x over previous
//
#include <hip/hip_runtime.h>

// RPN target generation for MI355X — 2-node pipeline: full-G 2-anchor main -> tiny finalize.
// Outputs (float32, concat): [0,A) rpn_match; [A,5A) rpn_bbox (A x 4); [5A] num_positives.
//
// Calibrated lessons (R2-R12):
//  * same-address device atomics ~100ns/op, serialized per address -> depth O(32) max.
//  * DS queue in-order -> per-lane VGPR bitmask in hot loop + sparse post-loop LDS drain.
//  * per-block __threadfence() = L2 writeback on multi-XCD gfx950 (R9 +100us) ->
//    cross-block visibility ONLY via kernel boundaries.
//  * single-block latency-streaming trap (R8) -> finalize reads 40KB with 1024 thr.
//  * no memsets: biased keys beat 0xAA poison; other ws slots fully overwritten.
//  * 2 anchors/thread sharing one ds_read = 2 independent chains -> pairs2 54.5us vs
//    main2 62us at same occupancy (R7 vs R11 A/B). This kernel: full-G x 2-anchor.
//  * inner loop fully unrolled (64) -> mask bit is a compile-time constant.
//
// ws layout: [0,A*8) akey | [+G*16*8) gkeyS | [+nb*4) pcount | [+nb*4) fvmin

#define GMAX 256
#define SHARDS 16
#define KBIAS 0xC0000001u   // real key top-words >= 0xC0000002; 0xAAAAAAAA poison loses

// Faithful to the reference, including the intentional size "bug":
// gt_size = y2 + y1 (not y2 - y1); centre = 0.5 * (y1 + y2).
__device__ __forceinline__ float4 compute_deltas(float4 ab, float4 gb,
                                                 const float* __restrict__ sd) {
    float sy_g = gb.z + gb.x;   // box = (y1, x1, y2, x2) in (x,y,z,w)
    float sx_g = gb.w + gb.y;
    float sy_a = ab.z + ab.x;
    float sx_a = ab.w + ab.y;
    float4 d;
    d.x = (0.5f * (sy_g - sy_a) / sy_a) / sd[0];
    d.y = (0.5f * (sx_g - sx_a) / sx_a) / sd[1];
    d.z = logf(sy_g / sy_a) / sd[2];
    d.w = logf(sx_g / sx_a) / sd[3];
    return d;
}

__device__ __forceinline__ float iou_of(float4 ab, float a_area, float4 gb) {
    float y1 = fmaxf(ab.x, gb.x);
    float x1 = fmaxf(ab.y, gb.y);
    float y2 = fminf(ab.z, gb.z);
    float x2 = fminf(ab.w, gb.w);
    float inter = fmaxf(y2 - y1, 0.f) * fmaxf(x2 - x1, 0.f);
    float garea = (gb.z - gb.x) * (gb.w - gb.y);
    float uni = (a_area + garea) - inter;
    return inter * __builtin_amdgcn_rcpf(uni);   // exact 0 if inter==0
}

// ---------- kernel 1: full-G sweep, 2 anchors/thread, outputs inline ----------
__global__ __launch_bounds__(256) void rpn_main3(
    const float4* __restrict__ anchors,       // [A]
    const int* __restrict__ valid,            // [A] jnp bool as int32
    const int* __restrict__ cls,              // [G]
    const float4* __restrict__ gt,            // [G]
    const float* __restrict__ stdev,          // [4]
    float* __restrict__ out,                  // [5A+1]
    unsigned long long* __restrict__ akey,    // [A] plain stores (best_bits:32|bg:32)
    unsigned long long* __restrict__ gkeyS,   // [G*SHARDS] biased keys, poison-ok
    int* __restrict__ pcount,                 // [nb] plain stores
    int* __restrict__ fvmin,                  // [nb] plain stores (min valid ai, else INT_MAX)
    int A, int halfA, int G)
{
    __shared__ float4 s_gt[GMAX];
    __shared__ float s_area[GMAX];            // per-gt area, loop-invariant
    __shared__ float s_crowdf[GMAX];
    __shared__ unsigned long long s_key[GMAX];
    __shared__ int s_anycrowd;
    __shared__ int s_cnt;
    __shared__ int s_fv;

    const int tid = threadIdx.x;
    if (tid == 0) { s_anycrowd = 0; s_cnt = 0; s_fv = 0x7FFFFFFF; }
    s_key[tid] = 0ULL;
    if (tid < G) {
        float4 b = gt[tid];
        s_gt[tid] = b;
        s_area[tid] = (b.z - b.x) * (b.w - b.y);
        int c = cls[tid];
        s_crowdf[tid] = (c < 0) ? 1.0f : 0.0f;
        if (c < 0) s_anycrowd = 1;            // benign race, same value
    }
    __syncthreads();
    const int any_crowd = s_anycrowd;

    // two coalesced anchor streams: [0,halfA) and [halfA,A)
    const int ai0 = blockIdx.x * 256 + tid;
    const int ai1 = ai0 + halfA;
    const bool ir0 = (ai0 < halfA), ir1 = (ai1 < A);
    float4 a0 = ir0 ? anchors[ai0] : make_float4(0.f, 0.f, 1.f, 1.f);
    float4 a1 = ir1 ? anchors[ai1] : make_float4(0.f, 0.f, 1.f, 1.f);
    const bool v0 = ir0 && (valid[ai0] != 0);
    const bool v1 = ir1 && (valid[ai1] != 0);
    const float ar0 = (a0.z - a0.x) * (a0.w - a0.y);
    const float ar1 = (a1.z - a1.x) * (a1.w - a1.y);

    float b0v, b1v;
    int bg0 = 0, bg1 = 0;
    float cm0 = 0.0f, cm1 = 0.0f;
    unsigned long long ma[4] = {0ULL, 0ULL, 0ULL, 0ULL};
    unsigned long long mb[4] = {0ULL, 0ULL, 0ULL, 0ULL};

    if (!any_crowd && G == GMAX) {
        // ---- fast path: inner 64 fully unrolled (constant mask bits) ----
        b0v = -1.0f; b1v = -1.0f;
        for (int w = 0; w < 4; ++w) {
            unsigned long long mm0 = 0ULL, mm1 = 0ULL;
            const int gbase = w << 6;
            #pragma unroll
            for (int j = 0; j < 64; ++j) {
                const int g = gbase + j;
                float4 gb = s_gt[g];           // one ds_read_b128 feeds 2 anchors
                float ga = s_area[g];
                // anchor 0
                {
                    float y1 = fmaxf(a0.x, gb.x), x1 = fmaxf(a0.y, gb.y);
                    float y2 = fminf(a0.z, gb.z), x2 = fminf(a0.w, gb.w);
                    float inter = fmaxf(y2 - y1, 0.f) * fmaxf(x2 - x1, 0.f);
                    float iou = inter * __builtin_amdgcn_rcpf((ar0 + ga) - inter);
                    if (iou > b0v) { b0v = iou; bg0 = g; }     // first-index tie-break
                    if (iou > 0.0f) mm0 |= (1ULL << j);        // constant bit
                }
                // anchor 1
                {
                    float y1 = fmaxf(a1.x, gb.x), x1 = fmaxf(a1.y, gb.y);
                    float y2 = fminf(a1.z, gb.z), x2 = fminf(a1.w, gb.w);
                    float inter = fmaxf(y2 - y1, 0.f) * fmaxf(x2 - x1, 0.f);
                    float iou = inter * __builtin_amdgcn_rcpf((ar1 + ga) - inter);
                    if (iou > b1v) { b1v = iou; bg1 = g; }
                    if (iou > 0.0f) mm1 |= (1ULL << j);
                }
            }
            ma[w] = mm0; mb[w] = mm1;
        }
    } else {
        // ---- general path: crowd / odd G (correctness-only) ----
        b0v = -2.0f; b1v = -2.0f;
        for (int g = 0; g < G; ++g) {
            float4 gb = s_gt[g];
            float cf = s_crowdf[g];
            float i0 = iou_of(a0, ar0, gb);
            float i1 = iou_of(a1, ar1, gb);
            float e0 = (cf != 0.0f) ? -1.0f : i0;
            float e1 = (cf != 0.0f) ? -1.0f : i1;
            if (e0 > b0v) { b0v = e0; bg0 = g; }
            if (e1 > b1v) { b1v = e1; bg1 = g; }
            cm0 = fmaxf(cm0, i0 * cf);
            cm1 = fmaxf(cm1, i1 * cf);
            if (cf == 0.0f) {
                if (i0 > 0.0f) ma[g >> 6] |= (1ULL << (g & 63));
                if (i1 > 0.0f) mb[g >> 6] |= (1ULL << (g & 63));
            }
        }
    }

    // ---- outputs: everything thread-local (full G) ----
    bool nc0 = any_crowd ? (cm0 < 0.001f) : true;
    bool nc1 = any_crowd ? (cm1 < 0.001f) : true;
    bool pos0 = (b0v >= 0.7f), pos1 = (b1v >= 0.7f);
    bool neg0 = (b0v < 0.3f) && nc0 && !pos0;
    bool neg1 = (b1v < 0.3f) && nc1 && !pos1;
    bool pv0 = pos0 && v0, pv1 = pos1 && v1;

    if (ir0) {
        out[ai0] = v0 ? (pos0 ? 1.0f : (neg0 ? -1.0f : 0.0f)) : 0.0f;
        float4 d = make_float4(0.f, 0.f, 0.f, 0.f);
        if (pv0) d = compute_deltas(a0, s_gt[bg0], stdev);
        ((float4*)(out + A))[ai0] = d;
        akey[ai0] = (((unsigned long long)__float_as_uint(b0v)) << 32) | (unsigned)bg0;
    }
    if (ir1) {
        out[ai1] = v1 ? (pos1 ? 1.0f : (neg1 ? -1.0f : 0.0f)) : 0.0f;
        float4 d = make_float4(0.f, 0.f, 0.f, 0.f);
        if (pv1) d = compute_deltas(a1, s_gt[bg1], stdev);
        ((float4*)(out + A))[ai1] = d;
        akey[ai1] = (((unsigned long long)__float_as_uint(b1v)) << 32) | (unsigned)bg1;
    }

    // ---- sparse drain (~5 bits/lane/anchor): rare LDS atomicMax into s_key ----
    if (v0) {
        const unsigned lokey = ~(unsigned)ai0;  // smaller ai -> larger lokey
        atomicMin(&s_fv, ai0);
        #pragma unroll
        for (int w = 0; w < 4; ++w) {
            unsigned long long m = ma[w];
            while (m != 0ULL) {
                int j = __builtin_ctzll(m); m &= (m - 1ULL);
                int g = (w << 6) + j;
                float iou = iou_of(a0, ar0, s_gt[g]);
                atomicMax(&s_key[g],
                    (((unsigned long long)(__float_as_uint(iou) + KBIAS)) << 32) | lokey);
            }
        }
    }
    if (v1) {
        const unsigned lokey = ~(unsigned)ai1;
        atomicMin(&s_fv, ai1);
        #pragma unroll
        for (int w = 0; w < 4; ++w) {
            unsigned long long m = mb[w];
            while (m != 0ULL) {
                int j = __builtin_ctzll(m); m &= (m - 1ULL);
                int g = (w << 6) + j;
                float iou = iou_of(a1, ar1, s_gt[g]);
                atomicMax(&s_key[g],
                    (((unsigned long long)(__float_as_uint(iou) + KBIAS)) << 32) | lokey);
            }
        }
    }

    unsigned long long bal = __ballot((int)pv0);
    unsigned long long bal1 = __ballot((int)pv1);
    if ((tid & 63) == 0)
        atomicAdd(&s_cnt, (int)(__popcll(bal) + __popcll(bal1)));   // LDS only
    __syncthreads();

    // sharded global merge: ~32-deep per address over G*SHARDS addresses;
    // biased keys beat 0xAA poison -> no memset node.
    if (tid < G && s_key[tid] != 0ULL)
        atomicMax(&gkeyS[(size_t)tid * SHARDS + (blockIdx.x & (SHARDS - 1))],
                  s_key[tid]);
    if (tid == 0) { pcount[blockIdx.x] = s_cnt; fvmin[blockIdx.x] = s_fv; }
}

// ---------- kernel 2: single-block finalize (1024 thr, ~36 KB reads) ----------
__global__ __launch_bounds__(1024) void rpn_finalize2(
    const float4* __restrict__ anchors,
    const int* __restrict__ valid,
    const int* __restrict__ cls,
    const float4* __restrict__ gt,
    const float* __restrict__ stdev,
    float* __restrict__ out,
    const unsigned long long* __restrict__ akey,
    const unsigned long long* __restrict__ gkeyS,
    const int* __restrict__ pcount,
    const int* __restrict__ fvmin,
    int nb, int A, int G)
{
    __shared__ float4 s_gt[GMAX];
    __shared__ float s_crowdf[GMAX];
    __shared__ unsigned long long s_red[GMAX];   // per-gt max key
    __shared__ int s_tot[1024];
    __shared__ int s_fvt[1024];
    __shared__ int s_cnt;

    const int tid = threadIdx.x;
    if (tid == 0) s_cnt = 0;
    if (tid < GMAX) s_red[tid] = 0ULL;
    if (tid < G) {
        s_gt[tid] = gt[tid];
        s_crowdf[tid] = (cls[tid] < 0) ? 1.0f : 0.0f;
    }
    __syncthreads();

    // reduce shard matrix (G*SHARDS u64, coalesced) into s_red via LDS atomics
    const int total = G * SHARDS;
    for (int i = tid; i < total; i += 1024) {
        unsigned long long k = gkeyS[i];       // 0xAA poison loses to real biased keys
        atomicMax(&s_red[i / SHARDS], k);
    }

    // sum pcount, min fvmin (coalesced)
    int acc = 0, fv = 0x7FFFFFFF;
    for (int i = tid; i < nb; i += 1024) {
        acc += pcount[i];
        fv = min(fv, fvmin[i]);
    }
    s_tot[tid] = acc;
    s_fvt[tid] = fv;
    __syncthreads();
    for (int s = 512; s > 0; s >>= 1) {
        if (tid < s) {
            s_tot[tid] += s_tot[tid + s];
            s_fvt[tid] = min(s_fvt[tid], s_fvt[tid + s]);
        }
        __syncthreads();
    }
    const int first_valid = s_fvt[0];

    if (tid < G && s_crowdf[tid] == 0.0f) {    // scatter value is False for crowd gts
        unsigned long long key = s_red[tid];
        const bool has = ((unsigned)(key >> 32) >= (KBIAS + 1u));  // poison/empty -> none
        int w = -1;
        if (has) {
            w = (int)(~(unsigned)(key & 0xFFFFFFFFull));
        } else if (first_valid != 0x7FFFFFFF) {
            // no valid anchor overlapped this gt: column argmax = first valid anchor
            w = first_valid;
        }
        if (w >= 0) {
            float old = atomicExch(out + w, 1.0f);   // <=256 ops, mostly distinct addrs
            if (old != 1.0f) {
                // flipped to positive: deltas use the anchor's OWN argmax (akey[w])
                int bg = (int)(unsigned)akey[w];
                ((float4*)(out + A))[w] = compute_deltas(anchors[w], s_gt[bg], stdev);
                atomicAdd(&s_cnt, 1);
            }
        }
    }
    __syncthreads();
    if (tid == 0) out[(size_t)5 * A] = (float)(s_tot[0] + s_cnt);
}

// ---------------- fallback: monolithic kernel (used only if ws too small) ------
__global__ __launch_bounds__(256) void rpn_fused(
    const float4* __restrict__ anchors, const int* __restrict__ valid,
    const int* __restrict__ cls, const float4* __restrict__ gt,
    const float* __restrict__ stdev, float* __restrict__ out,
    unsigned long long* __restrict__ gkey, unsigned* __restrict__ done,
    int* __restrict__ cnt, int A, int G)
{
    __shared__ float4 s_gt[GMAX];
    __shared__ float s_crowdf[GMAX];
    __shared__ unsigned long long s_key[GMAX];
    __shared__ int s_anycrowd; __shared__ int s_cnt; __shared__ int s_islast;

    const int tid = threadIdx.x;
    if (tid == 0) { s_anycrowd = 0; s_cnt = 0; }
    if (tid < G) {
        s_gt[tid] = gt[tid];
        int c = cls[tid];
        s_crowdf[tid] = (c < 0) ? 1.0f : 0.0f;
        if (c < 0) s_anycrowd = 1;
        s_key[tid] = 0ULL;
    }
    __syncthreads();
    const int any_crowd = s_anycrowd;
    const int ai = blockIdx.x * 256 + tid;
    const bool in_range = (ai < A);
    float4 ab = in_range ? anchors[ai] : make_float4(0.f, 0.f, 1.f, 1.f);
    const bool v = in_range && (valid[ai] != 0);
    const float a_area = (ab.z - ab.x) * (ab.w - ab.y);
    const unsigned lokey = ~(unsigned)ai;

    float best = any_crowd ? -2.0f : -1.0f;
    int bg = 0; float crowd_max = 0.0f;
    unsigned long long ovmask[4];
    #pragma unroll
    for (int w = 0; w < 4; ++w) {
        unsigned long long m = 0ULL;
        #pragma unroll 4
        for (int j = 0; j < 64; ++j) {
            int g = (w << 6) + j;
            if (g >= G) break;
            float iou = iou_of(ab, a_area, s_gt[g]);
            float cf = s_crowdf[g];
            float eff = (any_crowd && cf != 0.0f) ? -1.0f : iou;
            if (eff > best) { best = eff; bg = g; }
            if (any_crowd) crowd_max = fmaxf(crowd_max, iou * cf);
            if (v && (cf == 0.0f) && iou > 0.0f) m |= (1ULL << j);
        }
        ovmask[w] = m;
    }
    #pragma unroll
    for (int w = 0; w < 4; ++w) {
        unsigned long long m = ovmask[w];
        while (m != 0ULL) {
            int j = __builtin_ctzll(m); m &= (m - 1ULL);
            int g = (w << 6) + j;
            float iou = iou_of(ab, a_area, s_gt[g]);
            atomicMax(&s_key[g],
                (((unsigned long long)(__float_as_uint(iou) + 1u)) << 32) | lokey);
        }
    }
    bool no_crowd = any_crowd ? (crowd_max < 0.001f) : true;
    bool pos = (best >= 0.7f);
    bool neg = (best < 0.3f) && no_crowd && !pos;
    unsigned long long pv = __ballot((int)(in_range && pos && v));
    if ((tid & 63) == 0) atomicAdd(&s_cnt, (int)__popcll(pv));
    if (in_range) {
        out[ai] = v ? (pos ? 1.0f : (neg ? -1.0f : 0.0f)) : 0.0f;
        float4 d = make_float4(0.f, 0.f, 0.f, 0.f);
        if (pos && v) d = compute_deltas(ab, s_gt[bg], stdev);
        ((float4*)(out + A))[ai] = d;
    }
    __syncthreads();
    if (tid < G && s_key[tid] != 0ULL) atomicMax(&gkey[tid], s_key[tid]);
    if (tid == 0 && s_cnt > 0) atomicAdd(cnt, s_cnt);
    __threadfence();
    if (tid == 0) {
        unsigned prev = atomicAdd(done, 1u);
        s_islast = (prev == gridDim.x - 1);
        s_cnt = 0;
    }
    __syncthreads();
    if (!s_islast) return;
    __threadfence();
    if (tid < G && s_crowdf[tid] == 0.0f) {
        unsigned long long key = gkey[tid];
        int w;
        if (key != 0ULL) w = (int)(~(unsigned)(key & 0xFFFFFFFFull));
        else { w = 0; for (int i = 0; i < A; ++i) { if (valid[i] != 0) { w = i; break; } } }
        if (valid[w] != 0) {
            float old = atomicExch(out + w, 1.0f);
            if (old != 1.0f) {
                float4 ab2 = anchors[w];
                float a2 = (ab2.z - ab2.x) * (ab2.w - ab2.y);
                float b2 = -2.0f; int g2 = 0;
                for (int g = 0; g < G; ++g) {
                    float iou = iou_of(ab2, a2, s_gt[g]);
                    float eff = (s_crowdf[g] != 0.0f) ? -1.0f : iou;
                    if (eff > b2) { b2 = eff; g2 = g; }
                }
                ((float4*)(out + A))[w] = compute_deltas(ab2, s_gt[g2], stdev);
                atomicAdd(&s_cnt, 1);
            }
        }
    }
    __syncthreads();
    if (tid == 0) out[(size_t)5 * A] = (float)(*cnt + s_cnt);
}

extern "C" void kernel_launch(void* const* d_in, const int* in_sizes, int n_in,
                              void* d_out, int out_size, void* d_ws, size_t ws_size,
                              hipStream_t stream) {
    const float4* anchors = (const float4*)d_in[0];
    const int* valid      = (const int*)d_in[1];   // jnp bool -> int32 per element
    const int* cls        = (const int*)d_in[2];
    const float4* gt      = (const float4*)d_in[3];
    const float* stdev    = (const float*)d_in[4];
    float* out            = (float*)d_out;

    const int A = in_sizes[0] / 4;
    const int G = in_sizes[2];                     // 256
    const int halfA = (A + 1) / 2;                 // 130944
    const int nb3 = (halfA + 255) / 256;           // 512 blocks

    const size_t akey_bytes  = (size_t)A * 8;
    const size_t shard_bytes = (size_t)G * SHARDS * 8;
    const size_t pcnt_bytes  = (size_t)nb3 * 4;
    const size_t fv_bytes    = (size_t)nb3 * 4;
    const size_t needed = akey_bytes + shard_bytes + pcnt_bytes + fv_bytes;

    if (ws_size >= needed && G <= GMAX) {
        char* p = (char*)d_ws;
        unsigned long long* akey  = (unsigned long long*)p;          p += akey_bytes;
        unsigned long long* gkeyS = (unsigned long long*)p;          p += shard_bytes;
        int* pcount               = (int*)p;                         p += pcnt_bytes;
        int* fvmin                = (int*)p;

        rpn_main3<<<nb3, 256, 0, stream>>>(anchors, valid, cls, gt, stdev, out,
                                           akey, gkeyS, pcount, fvmin, A, halfA, G);
        rpn_finalize2<<<1, 1024, 0, stream>>>(anchors, valid, cls, gt, stdev, out,
                                              akey, gkeyS, pcount, fvmin, nb3, A, G);
    } else {
        const int nb = (A + 255) / 256;
        unsigned long long* gkey = (unsigned long long*)d_ws;
        unsigned* done = (unsigned*)((char*)d_ws + 2048);
        int* cnt       = (int*)((char*)d_ws + 2052);
        hipMemsetAsync(d_ws, 0, 2056, stream);
        rpn_fused<<<nb, 256, 0, stream>>>(anchors, valid, cls, gt, stdev, out,
                                          gkey, done, cnt, A, G);
    }
}

// Round 14
// 124.692 us; speedup vs baseline: 1.8919x; 1.0181x over previous
//
#include <hip/hip_runtime.h>

// RPN target generation for MI355X — 2-node pipeline: half-anchor-split main -> tiny finalize.
// Outputs (float32, concat): [0,A) rpn_match; [A,5A) rpn_bbox (A x 4); [5A] num_positives.
//
// Calibrated lessons (R2-R13):
//  * same-address device atomics ~100ns/op serialized per address -> depth O(64) max.
//  * DS queue in-order -> per-lane VGPR bitmask in hot loop + sparse post-loop LDS drain.
//  * per-block __threadfence() = L2 writeback on multi-XCD gfx950 -> cross-block
//    visibility ONLY via kernel boundaries (2 nodes).
//  * single-block latency-streaming trap -> finalize reads 64KB with 1024 thr.
//  * no memsets: biased keys beat 0xAA ws poison under atomicMax.
//  * R12 vs R13 A/B: 2-anchor ILP cut VALU issue 21% but halved TLP (2 blk/CU) ->
//    net zero. R14: 2 THREADS per anchor (each scans half of G, shfl_xor merge)
//    -> 2046 blocks = 32 waves/CU (2x TLP) AND halved per-thread chain length,
//    with outputs still thread-local (even lane).
//
// ws layout: [0,A*8) akey | [+G*32*8) gkeyS | [+nb*4) pcount | [+nb*4) fvmin

#define GMAX 256
#define SHARDS 32
#define KBIAS 0xC0000001u   // real key top-words >= 0xC0000002; 0xAAAAAAAA poison loses

// Faithful to the reference, including the intentional size "bug":
// gt_size = y2 + y1 (not y2 - y1); centre = 0.5 * (y1 + y2).
__device__ __forceinline__ float4 compute_deltas(float4 ab, float4 gb,
                                                 const float* __restrict__ sd) {
    float sy_g = gb.z + gb.x;   // box = (y1, x1, y2, x2) in (x,y,z,w)
    float sx_g = gb.w + gb.y;
    float sy_a = ab.z + ab.x;
    float sx_a = ab.w + ab.y;
    float4 d;
    d.x = (0.5f * (sy_g - sy_a) / sy_a) / sd[0];
    d.y = (0.5f * (sx_g - sx_a) / sx_a) / sd[1];
    d.z = logf(sy_g / sy_a) / sd[2];
    d.w = logf(sx_g / sx_a) / sd[3];
    return d;
}

__device__ __forceinline__ float iou_of(float4 ab, float a_area, float4 gb) {
    float y1 = fmaxf(ab.x, gb.x);
    float x1 = fmaxf(ab.y, gb.y);
    float y2 = fminf(ab.z, gb.z);
    float x2 = fminf(ab.w, gb.w);
    float inter = fmaxf(y2 - y1, 0.f) * fmaxf(x2 - x1, 0.f);
    float garea = (gb.z - gb.x) * (gb.w - gb.y);
    float uni = (a_area + garea) - inter;
    return inter * __builtin_amdgcn_rcpf(uni);   // exact 0 if inter==0
}

// ---------- kernel 1: 2 threads/anchor (G split), outputs inline on even lane ----------
__global__ __launch_bounds__(256, 8) void rpn_main4(
    const float4* __restrict__ anchors,       // [A]
    const int* __restrict__ valid,            // [A] jnp bool as int32
    const int* __restrict__ cls,              // [G]
    const float4* __restrict__ gt,            // [G]
    const float* __restrict__ stdev,          // [4]
    float* __restrict__ out,                  // [5A+1]
    unsigned long long* __restrict__ akey,    // [A] plain stores (best_bits:32|bg:32)
    unsigned long long* __restrict__ gkeyS,   // [G*SHARDS] biased keys, poison-ok
    int* __restrict__ pcount,                 // [nb] plain stores
    int* __restrict__ fvmin,                  // [nb] plain stores (min valid ai, else INT_MAX)
    int A, int G)
{
    __shared__ float4 s_gt[GMAX];
    __shared__ float s_area[GMAX];
    __shared__ float s_crowdf[GMAX];
    __shared__ unsigned long long s_key[GMAX];
    __shared__ int s_anycrowd;
    __shared__ int s_cnt;
    __shared__ int s_fv;

    const int tid = threadIdx.x;
    if (tid == 0) { s_anycrowd = 0; s_cnt = 0; s_fv = 0x7FFFFFFF; }
    s_key[tid] = 0ULL;
    if (tid < G) {
        float4 b = gt[tid];
        s_gt[tid] = b;
        s_area[tid] = (b.z - b.x) * (b.w - b.y);
        int c = cls[tid];
        s_crowdf[tid] = (c < 0) ? 1.0f : 0.0f;
        if (c < 0) s_anycrowd = 1;            // benign race, same value
    }
    __syncthreads();
    const int any_crowd = s_anycrowd;

    // lane pair (2a, 2a+1) = anchor a, G-halves 0/1
    const int a  = tid >> 1;
    const int h  = tid & 1;
    const int ai = blockIdx.x * 128 + a;
    const bool ir = (ai < A);
    float4 ab = ir ? anchors[ai] : make_float4(0.f, 0.f, 1.f, 1.f);
    const bool v = ir && (valid[ai] != 0);
    const float a_area = (ab.z - ab.x) * (ab.w - ab.y);

    const int Gh = (G + 1) >> 1;
    const int g0 = h * Gh;
    const int gn = min(G - g0, Gh);           // may be < Gh for odd G

    float best;
    int bg = g0;
    float cm = 0.0f;
    unsigned long long mm0 = 0ULL, mm1 = 0ULL;

    if (!any_crowd && G == GMAX) {
        // ---- fast path: 128 gts/lane, inner 64 fully unrolled (const offsets+bits) ----
        best = -1.0f;
        const float4* gp = &s_gt[g0];          // per-lane base; offsets are immediates
        const float*  ap = &s_area[g0];
        for (int w = 0; w < 2; ++w) {
            unsigned long long m = 0ULL;
            const int base = w << 6;
            #pragma unroll
            for (int j = 0; j < 64; ++j) {
                const int gg = base + j;
                float4 gb = gp[gg];
                float y1 = fmaxf(ab.x, gb.x), x1 = fmaxf(ab.y, gb.y);
                float y2 = fminf(ab.z, gb.z), x2 = fminf(ab.w, gb.w);
                float inter = fmaxf(y2 - y1, 0.f) * fmaxf(x2 - x1, 0.f);
                float iou = inter * __builtin_amdgcn_rcpf((a_area + ap[gg]) - inter);
                if (iou > best) { best = iou; bg = g0 + gg; }   // first-index tie-break
                if (iou > 0.0f) m |= (1ULL << j);               // constant bit
            }
            if (w == 0) mm0 = m; else mm1 = m;
        }
    } else {
        // ---- general path: crowd / odd G (correctness-only) ----
        best = -2.0f;
        for (int gg = 0; gg < gn; ++gg) {
            const int g = g0 + gg;
            float4 gb = s_gt[g];
            float iou = iou_of(ab, a_area, gb);
            float cf = s_crowdf[g];
            float eff = (cf != 0.0f) ? -1.0f : iou;
            if (eff > best) { best = eff; bg = g; }
            cm = fmaxf(cm, iou * cf);
            if (cf == 0.0f && iou > 0.0f) {
                if (gg < 64) mm0 |= (1ULL << gg); else mm1 |= (1ULL << (gg - 64));
            }
        }
    }

    // ---- merge the two halves via adjacent-lane shuffle (convergent) ----
    {
        float ob  = __shfl_xor(best, 1);
        int   obg = __shfl_xor(bg, 1);
        float ocm = __shfl_xor(cm, 1);
        if (h == 0) {
            // other half's g indices are all larger -> strict > keeps first-index ties
            if (ob > best) { best = ob; bg = obg; }
            cm = fmaxf(cm, ocm);
        }
    }

    bool no_crowd = any_crowd ? (cm < 0.001f) : true;
    bool pos = (best >= 0.7f);
    bool neg = (best < 0.3f) && no_crowd && !pos;
    bool posv = (h == 0) && pos && v;

    if (ir && h == 0) {
        out[ai] = v ? (pos ? 1.0f : (neg ? -1.0f : 0.0f)) : 0.0f;
        float4 d = make_float4(0.f, 0.f, 0.f, 0.f);
        if (pos && v) d = compute_deltas(ab, s_gt[bg], stdev);
        ((float4*)(out + A))[ai] = d;
        akey[ai] = (((unsigned long long)__float_as_uint(best)) << 32) | (unsigned)bg;
    }

    // ---- sparse drain: each lane drains its OWN half's overlap bits ----
    if (v) {
        const unsigned lokey = ~(unsigned)ai;   // smaller ai -> larger lokey
        if (h == 0) atomicMin(&s_fv, ai);
        for (int w = 0; w < 2; ++w) {
            unsigned long long m = (w == 0) ? mm0 : mm1;
            while (m != 0ULL) {
                int j = __builtin_ctzll(m); m &= (m - 1ULL);
                int g = g0 + (w << 6) + j;
                float iou = iou_of(ab, a_area, s_gt[g]);
                atomicMax(&s_key[g],
                    (((unsigned long long)(__float_as_uint(iou) + KBIAS)) << 32) | lokey);
            }
        }
    }

    unsigned long long bal = __ballot((int)posv);
    if ((tid & 63) == 0) atomicAdd(&s_cnt, (int)__popcll(bal));   // LDS only
    __syncthreads();

    // sharded global merge: 2046/32 = 64-deep per address (calibrated ok);
    // biased keys beat 0xAA poison -> no memset node.
    if (tid < G && s_key[tid] != 0ULL)
        atomicMax(&gkeyS[(size_t)tid * SHARDS + (blockIdx.x & (SHARDS - 1))],
                  s_key[tid]);
    if (tid == 0) { pcount[blockIdx.x] = s_cnt; fvmin[blockIdx.x] = s_fv; }
}

// ---------- kernel 2: single-block finalize (1024 thr, ~72 KB reads) ----------
__global__ __launch_bounds__(1024) void rpn_finalize2(
    const float4* __restrict__ anchors,
    const int* __restrict__ valid,
    const int* __restrict__ cls,
    const float4* __restrict__ gt,
    const float* __restrict__ stdev,
    float* __restrict__ out,
    const unsigned long long* __restrict__ akey,
    const unsigned long long* __restrict__ gkeyS,
    const int* __restrict__ pcount,
    const int* __restrict__ fvmin,
    int nb, int A, int G)
{
    __shared__ float4 s_gt[GMAX];
    __shared__ float s_crowdf[GMAX];
    __shared__ unsigned long long s_red[GMAX];   // per-gt max key
    __shared__ int s_tot[1024];
    __shared__ int s_fvt[1024];
    __shared__ int s_cnt;

    const int tid = threadIdx.x;
    if (tid == 0) s_cnt = 0;
    if (tid < GMAX) s_red[tid] = 0ULL;
    if (tid < G) {
        s_gt[tid] = gt[tid];
        s_crowdf[tid] = (cls[tid] < 0) ? 1.0f : 0.0f;
    }
    __syncthreads();

    // reduce shard matrix (G*SHARDS u64, coalesced) into s_red via LDS atomics
    const int total = G * SHARDS;
    for (int i = tid; i < total; i += 1024) {
        unsigned long long k = gkeyS[i];       // 0xAA poison loses to real biased keys
        atomicMax(&s_red[i / SHARDS], k);
    }

    // sum pcount, min fvmin (coalesced)
    int acc = 0, fv = 0x7FFFFFFF;
    for (int i = tid; i < nb; i += 1024) {
        acc += pcount[i];
        fv = min(fv, fvmin[i]);
    }
    s_tot[tid] = acc;
    s_fvt[tid] = fv;
    __syncthreads();
    for (int s = 512; s > 0; s >>= 1) {
        if (tid < s) {
            s_tot[tid] += s_tot[tid + s];
            s_fvt[tid] = min(s_fvt[tid], s_fvt[tid + s]);
        }
        __syncthreads();
    }
    const int first_valid = s_fvt[0];

    if (tid < G && s_crowdf[tid] == 0.0f) {    // scatter value is False for crowd gts
        unsigned long long key = s_red[tid];
        const bool has = ((unsigned)(key >> 32) >= (KBIAS + 1u));  // poison/empty -> none
        int w = -1;
        if (has) {
            w = (int)(~(unsigned)(key & 0xFFFFFFFFull));
        } else if (first_valid != 0x7FFFFFFF) {
            // no valid anchor overlapped this gt: column argmax = first valid anchor
            w = first_valid;
        }
        if (w >= 0) {
            float old = atomicExch(out + w, 1.0f);   // <=256 ops, mostly distinct addrs
            if (old != 1.0f) {
                // flipped to positive: deltas use the anchor's OWN argmax (akey[w])
                int bg = (int)(unsigned)akey[w];
                ((float4*)(out + A))[w] = compute_deltas(anchors[w], s_gt[bg], stdev);
                atomicAdd(&s_cnt, 1);
            }
        }
    }
    __syncthreads();
    if (tid == 0) out[(size_t)5 * A] = (float)(s_tot[0] + s_cnt);
}

// ---------------- fallback: monolithic kernel (used only if ws too small) ------
__global__ __launch_bounds__(256) void rpn_fused(
    const float4* __restrict__ anchors, const int* __restrict__ valid,
    const int* __restrict__ cls, const float4* __restrict__ gt,
    const float* __restrict__ stdev, float* __restrict__ out,
    unsigned long long* __restrict__ gkey, unsigned* __restrict__ done,
    int* __restrict__ cnt, int A, int G)
{
    __shared__ float4 s_gt[GMAX];
    __shared__ float s_crowdf[GMAX];
    __shared__ unsigned long long s_key[GMAX];
    __shared__ int s_anycrowd; __shared__ int s_cnt; __shared__ int s_islast;

    const int tid = threadIdx.x;
    if (tid == 0) { s_anycrowd = 0; s_cnt = 0; }
    if (tid < G) {
        s_gt[tid] = gt[tid];
        int c = cls[tid];
        s_crowdf[tid] = (c < 0) ? 1.0f : 0.0f;
        if (c < 0) s_anycrowd = 1;
        s_key[tid] = 0ULL;
    }
    __syncthreads();
    const int any_crowd = s_anycrowd;
    const int ai = blockIdx.x * 256 + tid;
    const bool in_range = (ai < A);
    float4 ab = in_range ? anchors[ai] : make_float4(0.f, 0.f, 1.f, 1.f);
    const bool v = in_range && (valid[ai] != 0);
    const float a_area = (ab.z - ab.x) * (ab.w - ab.y);
    const unsigned lokey = ~(unsigned)ai;

    float best = any_crowd ? -2.0f : -1.0f;
    int bg = 0; float crowd_max = 0.0f;
    unsigned long long ovmask[4];
    #pragma unroll
    for (int w = 0; w < 4; ++w) {
        unsigned long long m = 0ULL;
        #pragma unroll 4
        for (int j = 0; j < 64; ++j) {
            int g = (w << 6) + j;
            if (g >= G) break;
            float iou = iou_of(ab, a_area, s_gt[g]);
            float cf = s_crowdf[g];
            float eff = (any_crowd && cf != 0.0f) ? -1.0f : iou;
            if (eff > best) { best = eff; bg = g; }
            if (any_crowd) crowd_max = fmaxf(crowd_max, iou * cf);
            if (v && (cf == 0.0f) && iou > 0.0f) m |= (1ULL << j);
        }
        ovmask[w] = m;
    }
    #pragma unroll
    for (int w = 0; w < 4; ++w) {
        unsigned long long m = ovmask[w];
        while (m != 0ULL) {
            int j = __builtin_ctzll(m); m &= (m - 1ULL);
            int g = (w << 6) + j;
            float iou = iou_of(ab, a_area, s_gt[g]);
            atomicMax(&s_key[g],
                (((unsigned long long)(__float_as_uint(iou) + 1u)) << 32) | lokey);
        }
    }
    bool no_crowd = any_crowd ? (crowd_max < 0.001f) : true;
    bool pos = (best >= 0.7f);
    bool neg = (best < 0.3f) && no_crowd && !pos;
    unsigned long long pv = __ballot((int)(in_range && pos && v));
    if ((tid & 63) == 0) atomicAdd(&s_cnt, (int)__popcll(pv));
    if (in_range) {
        out[ai] = v ? (pos ? 1.0f : (neg ? -1.0f : 0.0f)) : 0.0f;
        float4 d = make_float4(0.f, 0.f, 0.f, 0.f);
        if (pos && v) d = compute_deltas(ab, s_gt[bg], stdev);
        ((float4*)(out + A))[ai] = d;
    }
    __syncthreads();
    if (tid < G && s_key[tid] != 0ULL) atomicMax(&gkey[tid], s_key[tid]);
    if (tid == 0 && s_cnt > 0) atomicAdd(cnt, s_cnt);
    __threadfence();
    if (tid == 0) {
        unsigned prev = atomicAdd(done, 1u);
        s_islast = (prev == gridDim.x - 1);
        s_cnt = 0;
    }
    __syncthreads();
    if (!s_islast) return;
    __threadfence();
    if (tid < G && s_crowdf[tid] == 0.0f) {
        unsigned long long key = gkey[tid];
        int w;
        if (key != 0ULL) w = (int)(~(unsigned)(key & 0xFFFFFFFFull));
        else { w = 0; for (int i = 0; i < A; ++i) { if (valid[i] != 0) { w = i; break; } } }
        if (valid[w] != 0) {
            float old = atomicExch(out + w, 1.0f);
            if (old != 1.0f) {
                float4 ab2 = anchors[w];
                float a2 = (ab2.z - ab2.x) * (ab2.w - ab2.y);
                float b2 = -2.0f; int g2 = 0;
                for (int g = 0; g < G; ++g) {
                    float iou = iou_of(ab2, a2, s_gt[g]);
                    float eff = (s_crowdf[g] != 0.0f) ? -1.0f : iou;
                    if (eff > b2) { b2 = eff; g2 = g; }
                }
                ((float4*)(out + A))[w] = compute_deltas(ab2, s_gt[g2], stdev);
                atomicAdd(&s_cnt, 1);
            }
        }
    }
    __syncthreads();
    if (tid == 0) out[(size_t)5 * A] = (float)(*cnt + s_cnt);
}

extern "C" void kernel_launch(void* const* d_in, const int* in_sizes, int n_in,
                              void* d_out, int out_size, void* d_ws, size_t ws_size,
                              hipStream_t stream) {
    const float4* anchors = (const float4*)d_in[0];
    const int* valid      = (const int*)d_in[1];   // jnp bool -> int32 per element
    const int* cls        = (const int*)d_in[2];
    const float4* gt      = (const float4*)d_in[3];
    const float* stdev    = (const float*)d_in[4];
    float* out            = (float*)d_out;

    const int A = in_sizes[0] / 4;
    const int G = in_sizes[2];                     // 256
    const int nb4 = (A + 127) / 128;               // 2046 blocks (128 anchors/block)

    const size_t akey_bytes  = (size_t)A * 8;
    const size_t shard_bytes = (size_t)G * SHARDS * 8;
    const size_t pcnt_bytes  = (size_t)nb4 * 4;
    const size_t fv_bytes    = (size_t)nb4 * 4;
    const size_t needed = akey_bytes + shard_bytes + pcnt_bytes + fv_bytes;

    if (ws_size >= needed && G <= GMAX) {
        char* p = (char*)d_ws;
        unsigned long long* akey  = (unsigned long long*)p;          p += akey_bytes;
        unsigned long long* gkeyS = (unsigned long long*)p;          p += shard_bytes;
        int* pcount               = (int*)p;                         p += pcnt_bytes;
        int* fvmin                = (int*)p;

        rpn_main4<<<nb4, 256, 0, stream>>>(anchors, valid, cls, gt, stdev, out,
                                           akey, gkeyS, pcount, fvmin, A, G);
        rpn_finalize2<<<1, 1024, 0, stream>>>(anchors, valid, cls, gt, stdev, out,
                                              akey, gkeyS, pcount, fvmin, nb4, A, G);
    } else {
        const int nb = (A + 255) / 256;
        unsigned long long* gkey = (unsigned long long*)d_ws;
        unsigned* done = (unsigned*)((char*)d_ws + 2048);
        int* cnt       = (int*)((char*)d_ws + 2052);
        hipMemsetAsync(d_ws, 0, 2056, stream);
        rpn_fused<<<nb, 256, 0, stream>>>(anchors, valid, cls, gt, stdev, out,
                                          gkey, done, cnt, A, G);
    }
}